// Round 1
// baseline (324.280 us; speedup 1.0000x reference)
//
#include <hip/hip_runtime.h>
#include <hip/hip_bf16.h>
#include <stdint.h>

// ---------------------------------------------------------------------------
// SelfAttention: QKV = X@W + b ; S = QK^T/32 (mask -> -inf) ; O = softmax(S)@V
// B=4, S=2048, H=1024.  bf16 MFMA path (threshold is bf16-scale).
// ---------------------------------------------------------------------------

typedef __attribute__((ext_vector_type(8))) short bf16x8;   // 8 bf16 = 4 VGPRs
typedef __attribute__((ext_vector_type(4))) float f32x4;

__device__ __forceinline__ void async_cp16(const void* g, void* l) {
  __builtin_amdgcn_global_load_lds(
      (const __attribute__((address_space(1))) void*)g,
      (__attribute__((address_space(3))) void*)l, 16, 0, 0);
}

// --------------------------- fp32 -> bf16 convert ---------------------------
__global__ void cvt_f32_bf16(const float* __restrict__ s,
                             __hip_bfloat16* __restrict__ d, int n) {
  int i = (blockIdx.x * blockDim.x + threadIdx.x) * 4;
  if (i >= n) return;
  float4 f = *(const float4*)(s + i);
  __hip_bfloat16 o[4];
  o[0] = __float2bfloat16(f.x);
  o[1] = __float2bfloat16(f.y);
  o[2] = __float2bfloat16(f.z);
  o[3] = __float2bfloat16(f.w);
  *(ushort4*)(d + i) = *(const ushort4*)o;
}

// -------------------- fp32 -> bf16 transposed (W -> W^T) --------------------
// src: rows x cols fp32 (row-major). dst[c][r] = src[r][c] as bf16.
__global__ void transpose_cvt_f32(const float* __restrict__ src, int srcld,
                                  __hip_bfloat16* __restrict__ dst, int dstld) {
  __shared__ float tile[32][33];
  int bx = blockIdx.x * 32;   // src col
  int by = blockIdx.y * 32;   // src row
  int tx = threadIdx.x, ty = threadIdx.y;
#pragma unroll
  for (int j = 0; j < 4; ++j)
    tile[ty + j * 8][tx] = src[(int64_t)(by + ty + j * 8) * srcld + bx + tx];
  __syncthreads();
#pragma unroll
  for (int j = 0; j < 4; ++j)
    dst[(int64_t)(bx + ty + j * 8) * dstld + by + tx] =
        __float2bfloat16(tile[tx][ty + j * 8]);
}

// ----------------------- bf16 transposed (V -> V^T) ------------------------
__global__ void transpose_bf16(const __hip_bfloat16* __restrict__ src, int srcld,
                               int64_t sstride,
                               __hip_bfloat16* __restrict__ dst, int dstld,
                               int64_t dstride) {
  __shared__ __hip_bfloat16 tile[32][33];
  int z = blockIdx.z;
  src += (int64_t)z * sstride;
  dst += (int64_t)z * dstride;
  int bx = blockIdx.x * 32;   // src col (d)
  int by = blockIdx.y * 32;   // src row (s)
  int tx = threadIdx.x, ty = threadIdx.y;
#pragma unroll
  for (int j = 0; j < 4; ++j)
    tile[ty + j * 8][tx] = src[(int64_t)(by + ty + j * 8) * srcld + bx + tx];
  __syncthreads();
#pragma unroll
  for (int j = 0; j < 4; ++j)
    dst[(int64_t)(bx + ty + j * 8) * dstld + by + tx] = tile[tx][ty + j * 8];
}

// ------------------------------- GEMM core ---------------------------------
// C[M][N] = A[M][K] @ Bt[N][K]^T.   128x128 tile, 256 thr (2x2 waves of 64x64),
// BK=32, mfma_f32_16x16x32_bf16.
// MODE 0: C = acc + bias[n]              -> bf16   (QKV projection)
// MODE 1: C = mask[n] ? -1e30 : acc/32   -> fp32   (scores)
// MODE 2: C = acc                        -> fp32   (P @ V -> out)
template <int MODE>
__global__ __launch_bounds__(256) void gemm_bt(
    const __hip_bfloat16* __restrict__ Abase, int lda, int64_t strideA,
    const __hip_bfloat16* __restrict__ Btbase, int ldb, int64_t strideB,
    void* __restrict__ Cbase, int ldc, int64_t strideC, int Ksize,
    const float* __restrict__ bias, const int* __restrict__ maskbase,
    int64_t strideMask, float scale) {
  const int z = blockIdx.z;
  const __hip_bfloat16* A = Abase + z * strideA;
  const __hip_bfloat16* Bt = Btbase + z * strideB;

  const int tid = threadIdx.x;
  const int wave = tid >> 6, lane = tid & 63;
  const int quad = lane >> 4, tr = lane & 15;
  const int wm = wave & 1, wn = wave >> 1;
  const int m0 = blockIdx.y * 128, n0 = blockIdx.x * 128;

  __shared__ __hip_bfloat16 lsA[128 * 32];
  __shared__ __hip_bfloat16 lsB[128 * 32];

  // Staging: 16 chunks of 1KB (64 lanes x 16B). Chunks 0..7 = A rows, 8..15 = B.
  // Wave w issues chunks w*4 .. w*4+3. LDS dest is wave-uniform; HW adds lane*16B.
  const __hip_bfloat16* gsrc[4];
  __hip_bfloat16* ldst[4];
#pragma unroll
  for (int cc = 0; cc < 4; ++cc) {
    int c = wave * 4 + cc;
    int isA = (c < 8);
    int cr = isA ? c : (c - 8);
    int row = cr * 16 + (lane >> 2);
    int kc = (lane & 3) * 8;
    gsrc[cc] = isA ? (A + (int64_t)(m0 + row) * lda + kc)
                   : (Bt + (int64_t)(n0 + row) * ldb + kc);
    ldst[cc] = (isA ? lsA : lsB) + cr * 512;
  }

  f32x4 acc[4][4];
#pragma unroll
  for (int mi = 0; mi < 4; ++mi)
#pragma unroll
    for (int ni = 0; ni < 4; ++ni) acc[mi][ni] = (f32x4){0.f, 0.f, 0.f, 0.f};

  for (int k0 = 0; k0 < Ksize; k0 += 32) {
    __syncthreads();
#pragma unroll
    for (int cc = 0; cc < 4; ++cc) async_cp16(gsrc[cc] + k0, ldst[cc]);
    __syncthreads();

    bf16x8 af[4], bfv[4];
#pragma unroll
    for (int mi = 0; mi < 4; ++mi)
      af[mi] = *(const bf16x8*)(lsA + (wm * 64 + mi * 16 + tr) * 32 + quad * 8);
#pragma unroll
    for (int ni = 0; ni < 4; ++ni)
      bfv[ni] = *(const bf16x8*)(lsB + (wn * 64 + ni * 16 + tr) * 32 + quad * 8);
#pragma unroll
    for (int mi = 0; mi < 4; ++mi)
#pragma unroll
      for (int ni = 0; ni < 4; ++ni)
        acc[mi][ni] = __builtin_amdgcn_mfma_f32_16x16x32_bf16(
            af[mi], bfv[ni], acc[mi][ni], 0, 0, 0);
  }

  // Epilogue. D element (row,col) in 16x16 tile = (quad*4 + r, tr)  [m89]
  const int rowbase = m0 + wm * 64;
  const int colbase = n0 + wn * 64;
  if (MODE == 0) {
    __hip_bfloat16* C = (__hip_bfloat16*)Cbase;
#pragma unroll
    for (int ni = 0; ni < 4; ++ni) {
      int col = colbase + ni * 16 + tr;
      float bv = bias[col];
#pragma unroll
      for (int mi = 0; mi < 4; ++mi) {
        int row = rowbase + mi * 16 + quad * 4;
#pragma unroll
        for (int r = 0; r < 4; ++r)
          C[(int64_t)(row + r) * ldc + col] =
              __float2bfloat16(acc[mi][ni][r] + bv);
      }
    }
  } else if (MODE == 1) {
    float* C = (float*)Cbase + z * strideC;
    const int* mask = maskbase + z * strideMask;
#pragma unroll
    for (int ni = 0; ni < 4; ++ni) {
      int col = colbase + ni * 16 + tr;
      bool msk = (mask[col] != 0);
#pragma unroll
      for (int mi = 0; mi < 4; ++mi) {
        int row = rowbase + mi * 16 + quad * 4;
#pragma unroll
        for (int r = 0; r < 4; ++r)
          C[(int64_t)(row + r) * ldc + col] =
              msk ? -1e30f : acc[mi][ni][r] * scale;
      }
    }
  } else {
    float* C = (float*)Cbase + z * strideC;
#pragma unroll
    for (int ni = 0; ni < 4; ++ni) {
      int col = colbase + ni * 16 + tr;
#pragma unroll
      for (int mi = 0; mi < 4; ++mi) {
        int row = rowbase + mi * 16 + quad * 4;
#pragma unroll
        for (int r = 0; r < 4; ++r)
          C[(int64_t)(row + r) * ldc + col] = acc[mi][ni][r];
      }
    }
  }
}

// ------------------------------ row softmax --------------------------------
// One block per row of 2048 fp32 scores -> bf16 probabilities.
__global__ __launch_bounds__(256) void softmax_rows(
    const float* __restrict__ Sc, __hip_bfloat16* __restrict__ P) {
  const int64_t row = blockIdx.x;
  const float* s = Sc + row * 2048;
  __hip_bfloat16* p = P + row * 2048;
  const int t = threadIdx.x;
  const int wave = t >> 6, lane = t & 63;
  __shared__ float red[8];

  float v[8];
  float mx = -3.0e38f;
#pragma unroll
  for (int i = 0; i < 8; ++i) {
    v[i] = s[t + i * 256];
    mx = fmaxf(mx, v[i]);
  }
#pragma unroll
  for (int off = 32; off >= 1; off >>= 1) mx = fmaxf(mx, __shfl_xor(mx, off, 64));
  if (lane == 0) red[wave] = mx;
  __syncthreads();
  mx = fmaxf(fmaxf(red[0], red[1]), fmaxf(red[2], red[3]));

  float sum = 0.f;
#pragma unroll
  for (int i = 0; i < 8; ++i) {
    v[i] = exp2f((v[i] - mx) * 1.4426950408889634f);
    sum += v[i];
  }
#pragma unroll
  for (int off = 32; off >= 1; off >>= 1) sum += __shfl_xor(sum, off, 64);
  if (lane == 0) red[4 + wave] = sum;
  __syncthreads();
  sum = red[4] + red[5] + red[6] + red[7];
  float inv = 1.0f / sum;
#pragma unroll
  for (int i = 0; i < 8; ++i) p[t + i * 256] = __float2bfloat16(v[i] * inv);
}

// ------------------------------- launcher ----------------------------------
extern "C" void kernel_launch(void* const* d_in, const int* in_sizes, int n_in,
                              void* d_out, int out_size, void* d_ws,
                              size_t ws_size, hipStream_t stream) {
  const float* X = (const float*)d_in[0];        // (4,2048,1024) fp32
  const int* mask = (const int*)d_in[1];         // (4,2048) bool->int32 assumed
  const float* W = (const float*)d_in[2];        // (1024,3072) fp32
  const float* bias = (const float*)d_in[3];     // (3072,) fp32
  float* out = (float*)d_out;                    // (4,2048,1024) fp32

  char* ws = (char*)d_ws;
  auto alloc = [&](size_t bytes) {
    char* p = ws;
    ws += (bytes + 255) & ~(size_t)255;
    return p;
  };
  __hip_bfloat16* Xb = (__hip_bfloat16*)alloc(8192ULL * 1024 * 2);   // 16.8 MB
  __hip_bfloat16* Wt = (__hip_bfloat16*)alloc(3072ULL * 1024 * 2);   //  6.3 MB
  __hip_bfloat16* QKV = (__hip_bfloat16*)alloc(8192ULL * 3072 * 2);  // 50.3 MB
  __hip_bfloat16* Vt = (__hip_bfloat16*)alloc(4ULL * 1024 * 2048 * 2);  // 16.8 MB
  float* Sc = (float*)alloc(4ULL * 2048 * 2048 * 4);                 // 67.1 MB
  __hip_bfloat16* P = (__hip_bfloat16*)alloc(4ULL * 2048 * 2048 * 2);  // 33.6 MB

  // 1) X -> bf16
  cvt_f32_bf16<<<8192, 256, 0, stream>>>(X, Xb, 8192 * 1024);
  // 2) W -> W^T bf16  (Bt layout [N][K])
  transpose_cvt_f32<<<dim3(96, 32, 1), dim3(32, 8), 0, stream>>>(W, 3072, Wt,
                                                                 1024);
  // 3) QKV = Xb @ Wt^T + bias  -> bf16 (8192 x 3072)
  gemm_bt<0><<<dim3(24, 64, 1), 256, 0, stream>>>(
      Xb, 1024, 0, Wt, 1024, 0, (void*)QKV, 3072, 0, 1024, bias, nullptr, 0,
      1.0f);
  // 4) V -> V^T bf16 per batch (d x s)
  transpose_bf16<<<dim3(32, 64, 4), dim3(32, 8), 0, stream>>>(
      QKV + 2048, 3072, 2048LL * 3072, Vt, 2048, 1024LL * 2048);
  // 5) scores = Q @ K^T / 32, mask -> -1e30  (fp32, per batch 2048x2048)
  gemm_bt<1><<<dim3(16, 16, 4), 256, 0, stream>>>(
      QKV, 3072, 2048LL * 3072, QKV + 1024, 3072, 2048LL * 3072, (void*)Sc,
      2048, 2048LL * 2048, 1024, nullptr, mask, 2048, 0.03125f);
  // 6) P = softmax(scores) -> bf16
  softmax_rows<<<8192, 256, 0, stream>>>(Sc, P);
  // 7) out = P @ Vt^T  (fp32, per batch 2048x1024)
  gemm_bt<2><<<dim3(8, 16, 4), 256, 0, stream>>>(
      P, 2048, 2048LL * 2048, Vt, 2048, 1024LL * 2048, (void*)out, 1024,
      2048LL * 1024, 2048, nullptr, nullptr, 0, 1.0f);
}

// Round 2
// 322.359 us; speedup vs baseline: 1.0060x; 1.0060x over previous
//
#include <hip/hip_runtime.h>
#include <hip/hip_bf16.h>
#include <stdint.h>

// ---------------------------------------------------------------------------
// SelfAttention: QKV = X@W + b ; S = QK^T/32 (mask -> -inf) ; O = softmax(S)@V
// B=4, S=2048, H=1024.  bf16 MFMA path.
// R2: XOR-swizzled LDS tiles (kills the 4-way ds_read_b128 bank conflicts
//     measured in R1: 6.29M conflict cycles on the QKV gemm), float4 softmax.
// ---------------------------------------------------------------------------

typedef __attribute__((ext_vector_type(8))) short bf16x8;   // 8 bf16 = 4 VGPRs
typedef __attribute__((ext_vector_type(4))) float f32x4;

__device__ __forceinline__ void async_cp16(const void* g, void* l) {
  __builtin_amdgcn_global_load_lds(
      (const __attribute__((address_space(1))) void*)g,
      (__attribute__((address_space(3))) void*)l, 16, 0, 0);
}

// --------------------------- fp32 -> bf16 convert ---------------------------
__global__ void cvt_f32_bf16(const float* __restrict__ s,
                             __hip_bfloat16* __restrict__ d, int n) {
  int i = (blockIdx.x * blockDim.x + threadIdx.x) * 4;
  if (i >= n) return;
  float4 f = *(const float4*)(s + i);
  __hip_bfloat16 o[4];
  o[0] = __float2bfloat16(f.x);
  o[1] = __float2bfloat16(f.y);
  o[2] = __float2bfloat16(f.z);
  o[3] = __float2bfloat16(f.w);
  *(ushort4*)(d + i) = *(const ushort4*)o;
}

// -------------------- fp32 -> bf16 transposed (W -> W^T) --------------------
__global__ void transpose_cvt_f32(const float* __restrict__ src, int srcld,
                                  __hip_bfloat16* __restrict__ dst, int dstld) {
  __shared__ float tile[32][33];
  int bx = blockIdx.x * 32;   // src col
  int by = blockIdx.y * 32;   // src row
  int tx = threadIdx.x, ty = threadIdx.y;
#pragma unroll
  for (int j = 0; j < 4; ++j)
    tile[ty + j * 8][tx] = src[(int64_t)(by + ty + j * 8) * srcld + bx + tx];
  __syncthreads();
#pragma unroll
  for (int j = 0; j < 4; ++j)
    dst[(int64_t)(bx + ty + j * 8) * dstld + by + tx] =
        __float2bfloat16(tile[tx][ty + j * 8]);
}

// ----------------------- bf16 transposed (V -> V^T) ------------------------
__global__ void transpose_bf16(const __hip_bfloat16* __restrict__ src, int srcld,
                               int64_t sstride,
                               __hip_bfloat16* __restrict__ dst, int dstld,
                               int64_t dstride) {
  __shared__ __hip_bfloat16 tile[32][33];
  int z = blockIdx.z;
  src += (int64_t)z * sstride;
  dst += (int64_t)z * dstride;
  int bx = blockIdx.x * 32;   // src col (d)
  int by = blockIdx.y * 32;   // src row (s)
  int tx = threadIdx.x, ty = threadIdx.y;
#pragma unroll
  for (int j = 0; j < 4; ++j)
    tile[ty + j * 8][tx] = src[(int64_t)(by + ty + j * 8) * srcld + bx + tx];
  __syncthreads();
#pragma unroll
  for (int j = 0; j < 4; ++j)
    dst[(int64_t)(bx + ty + j * 8) * dstld + by + tx] = tile[tx][ty + j * 8];
}

// ------------------------------- GEMM core ---------------------------------
// C[M][N] = A[M][K] @ Bt[N][K]^T.   128x128 tile, 256 thr (2x2 waves of 64x64),
// BK=32, mfma_f32_16x16x32_bf16.
//
// LDS layout is XOR-swizzled: row r's logical 8-elem k-chunk c lives at
// physical slot c ^ ((r>>1)&3). Staging achieves this by permuting the GLOBAL
// source chunk per lane (global_load_lds forces LDS dest = base + lane*16B):
// lane l fetches logical chunk (l&3) ^ ((l>>3)&3) of row (l>>2) — same 64B
// global segments, so coalescing is unchanged. Fragment reads at
// slot = quad ^ ((tr>>1)&3) are then bank-conflict-free (any aligned 8-lane
// group covers all 32 banks exactly once).
//
// MODE 0: C = acc + bias[n]              -> bf16   (QKV projection)
// MODE 1: C = mask[n] ? -1e30 : acc/32   -> fp32   (scores)
// MODE 2: C = acc                        -> fp32   (P @ V -> out)
template <int MODE>
__global__ __launch_bounds__(256) void gemm_bt(
    const __hip_bfloat16* __restrict__ Abase, int lda, int64_t strideA,
    const __hip_bfloat16* __restrict__ Btbase, int ldb, int64_t strideB,
    void* __restrict__ Cbase, int ldc, int64_t strideC, int Ksize,
    const float* __restrict__ bias, const int* __restrict__ maskbase,
    int64_t strideMask, float scale) {
  const int z = blockIdx.z;
  const __hip_bfloat16* A = Abase + z * strideA;
  const __hip_bfloat16* Bt = Btbase + z * strideB;

  const int tid = threadIdx.x;
  const int wave = tid >> 6, lane = tid & 63;
  const int quad = lane >> 4, tr = lane & 15;
  const int wm = wave & 1, wn = wave >> 1;
  const int m0 = blockIdx.y * 128, n0 = blockIdx.x * 128;

  __shared__ __hip_bfloat16 lsA[128 * 32];
  __shared__ __hip_bfloat16 lsB[128 * 32];

  // Staging: 16 chunks of 1KB (64 lanes x 16B). Chunks 0..7 = A rows, 8..15 = B.
  // Wave w issues chunks w*4 .. w*4+3. Swizzled source chunk (see header).
  const __hip_bfloat16* gsrc[4];
  __hip_bfloat16* ldst[4];
  {
    const int srow = lane >> 2;
    const int kc = (((lane & 3) ^ ((lane >> 3) & 3)) * 8);
#pragma unroll
    for (int cc = 0; cc < 4; ++cc) {
      int c = wave * 4 + cc;
      int isA = (c < 8);
      int cr = isA ? c : (c - 8);
      int row = cr * 16 + srow;
      gsrc[cc] = isA ? (A + (int64_t)(m0 + row) * lda + kc)
                     : (Bt + (int64_t)(n0 + row) * ldb + kc);
      ldst[cc] = (isA ? lsA : lsB) + cr * 512;
    }
  }

  f32x4 acc[4][4];
#pragma unroll
  for (int mi = 0; mi < 4; ++mi)
#pragma unroll
    for (int ni = 0; ni < 4; ++ni) acc[mi][ni] = (f32x4){0.f, 0.f, 0.f, 0.f};

  // Swizzled fragment slot: row = (multiple of 16) + tr  ->  (row>>1)&3 ==
  // (tr>>1)&3, so the slot is lane-only.
  const int slot = quad ^ ((tr >> 1) & 3);

  for (int k0 = 0; k0 < Ksize; k0 += 32) {
    __syncthreads();
#pragma unroll
    for (int cc = 0; cc < 4; ++cc) async_cp16(gsrc[cc] + k0, ldst[cc]);
    __syncthreads();

    bf16x8 af[4], bfv[4];
#pragma unroll
    for (int mi = 0; mi < 4; ++mi)
      af[mi] = *(const bf16x8*)(lsA + (wm * 64 + mi * 16 + tr) * 32 + slot * 8);
#pragma unroll
    for (int ni = 0; ni < 4; ++ni)
      bfv[ni] = *(const bf16x8*)(lsB + (wn * 64 + ni * 16 + tr) * 32 + slot * 8);
#pragma unroll
    for (int mi = 0; mi < 4; ++mi)
#pragma unroll
      for (int ni = 0; ni < 4; ++ni)
        acc[mi][ni] = __builtin_amdgcn_mfma_f32_16x16x32_bf16(
            af[mi], bfv[ni], acc[mi][ni], 0, 0, 0);
  }

  // Epilogue. D element (row,col) in 16x16 tile = (quad*4 + r, tr)  [m89]
  const int rowbase = m0 + wm * 64;
  const int colbase = n0 + wn * 64;
  if (MODE == 0) {
    __hip_bfloat16* C = (__hip_bfloat16*)Cbase;
#pragma unroll
    for (int ni = 0; ni < 4; ++ni) {
      int col = colbase + ni * 16 + tr;
      float bv = bias[col];
#pragma unroll
      for (int mi = 0; mi < 4; ++mi) {
        int row = rowbase + mi * 16 + quad * 4;
#pragma unroll
        for (int r = 0; r < 4; ++r)
          C[(int64_t)(row + r) * ldc + col] =
              __float2bfloat16(acc[mi][ni][r] + bv);
      }
    }
  } else if (MODE == 1) {
    float* C = (float*)Cbase + z * strideC;
    const int* mask = maskbase + z * strideMask;
#pragma unroll
    for (int ni = 0; ni < 4; ++ni) {
      int col = colbase + ni * 16 + tr;
      bool msk = (mask[col] != 0);
#pragma unroll
      for (int mi = 0; mi < 4; ++mi) {
        int row = rowbase + mi * 16 + quad * 4;
#pragma unroll
        for (int r = 0; r < 4; ++r)
          C[(int64_t)(row + r) * ldc + col] =
              msk ? -1e30f : acc[mi][ni][r] * scale;
      }
    }
  } else {
    float* C = (float*)Cbase + z * strideC;
#pragma unroll
    for (int ni = 0; ni < 4; ++ni) {
      int col = colbase + ni * 16 + tr;
#pragma unroll
      for (int mi = 0; mi < 4; ++mi) {
        int row = rowbase + mi * 16 + quad * 4;
#pragma unroll
        for (int r = 0; r < 4; ++r)
          C[(int64_t)(row + r) * ldc + col] = acc[mi][ni][r];
      }
    }
  }
}

// ------------------------------ row softmax --------------------------------
// One block per row of 2048 fp32 scores -> bf16 probabilities. float4 I/O.
__global__ __launch_bounds__(256) void softmax_rows(
    const float* __restrict__ Sc, __hip_bfloat16* __restrict__ P) {
  const int64_t row = blockIdx.x;
  const float4* s = (const float4*)(Sc + row * 2048);
  ushort4* p = (ushort4*)(P + row * 2048);
  const int t = threadIdx.x;
  const int wave = t >> 6, lane = t & 63;
  __shared__ float red[8];

  float4 v[2];
  v[0] = s[t];
  v[1] = s[t + 256];
  float* vf = (float*)v;
  float mx = -3.0e38f;
#pragma unroll
  for (int i = 0; i < 8; ++i) mx = fmaxf(mx, vf[i]);
#pragma unroll
  for (int off = 32; off >= 1; off >>= 1) mx = fmaxf(mx, __shfl_xor(mx, off, 64));
  if (lane == 0) red[wave] = mx;
  __syncthreads();
  mx = fmaxf(fmaxf(red[0], red[1]), fmaxf(red[2], red[3]));

  float sum = 0.f;
#pragma unroll
  for (int i = 0; i < 8; ++i) {
    vf[i] = exp2f((vf[i] - mx) * 1.4426950408889634f);
    sum += vf[i];
  }
#pragma unroll
  for (int off = 32; off >= 1; off >>= 1) sum += __shfl_xor(sum, off, 64);
  if (lane == 0) red[4 + wave] = sum;
  __syncthreads();
  sum = red[4] + red[5] + red[6] + red[7];
  float inv = 1.0f / sum;

  ushort4 o[2];
#pragma unroll
  for (int j = 0; j < 2; ++j) {
    __hip_bfloat16 h[4];
#pragma unroll
    for (int r = 0; r < 4; ++r) h[r] = __float2bfloat16(vf[j * 4 + r] * inv);
    o[j] = *(const ushort4*)h;
  }
  p[t] = o[0];
  p[t + 256] = o[1];
}

// ------------------------------- launcher ----------------------------------
extern "C" void kernel_launch(void* const* d_in, const int* in_sizes, int n_in,
                              void* d_out, int out_size, void* d_ws,
                              size_t ws_size, hipStream_t stream) {
  const float* X = (const float*)d_in[0];        // (4,2048,1024) fp32
  const int* mask = (const int*)d_in[1];         // (4,2048) bool->int32
  const float* W = (const float*)d_in[2];        // (1024,3072) fp32
  const float* bias = (const float*)d_in[3];     // (3072,) fp32
  float* out = (float*)d_out;                    // (4,2048,1024) fp32

  char* ws = (char*)d_ws;
  auto alloc = [&](size_t bytes) {
    char* p = ws;
    ws += (bytes + 255) & ~(size_t)255;
    return p;
  };
  __hip_bfloat16* Xb = (__hip_bfloat16*)alloc(8192ULL * 1024 * 2);   // 16.8 MB
  __hip_bfloat16* Wt = (__hip_bfloat16*)alloc(3072ULL * 1024 * 2);   //  6.3 MB
  __hip_bfloat16* QKV = (__hip_bfloat16*)alloc(8192ULL * 3072 * 2);  // 50.3 MB
  __hip_bfloat16* Vt = (__hip_bfloat16*)alloc(4ULL * 1024 * 2048 * 2);  // 16.8 MB
  float* Sc = (float*)alloc(4ULL * 2048 * 2048 * 4);                 // 67.1 MB
  __hip_bfloat16* P = (__hip_bfloat16*)alloc(4ULL * 2048 * 2048 * 2);  // 33.6 MB

  // 1) X -> bf16
  cvt_f32_bf16<<<8192, 256, 0, stream>>>(X, Xb, 8192 * 1024);
  // 2) W -> W^T bf16  (Bt layout [N][K])
  transpose_cvt_f32<<<dim3(96, 32, 1), dim3(32, 8), 0, stream>>>(W, 3072, Wt,
                                                                 1024);
  // 3) QKV = Xb @ Wt^T + bias  -> bf16 (8192 x 3072)
  gemm_bt<0><<<dim3(24, 64, 1), 256, 0, stream>>>(
      Xb, 1024, 0, Wt, 1024, 0, (void*)QKV, 3072, 0, 1024, bias, nullptr, 0,
      1.0f);
  // 4) V -> V^T bf16 per batch (d x s)
  transpose_bf16<<<dim3(32, 64, 4), dim3(32, 8), 0, stream>>>(
      QKV + 2048, 3072, 2048LL * 3072, Vt, 2048, 1024LL * 2048);
  // 5) scores = Q @ K^T / 32, mask -> -1e30  (fp32, per batch 2048x2048)
  gemm_bt<1><<<dim3(16, 16, 4), 256, 0, stream>>>(
      QKV, 3072, 2048LL * 3072, QKV + 1024, 3072, 2048LL * 3072, (void*)Sc,
      2048, 2048LL * 2048, 1024, nullptr, mask, 2048, 0.03125f);
  // 6) P = softmax(scores) -> bf16
  softmax_rows<<<8192, 256, 0, stream>>>(Sc, P);
  // 7) out = P @ Vt^T  (fp32, per batch 2048x1024)
  gemm_bt<2><<<dim3(8, 16, 4), 256, 0, stream>>>(
      P, 2048, 2048LL * 2048, Vt, 2048, 1024LL * 2048, (void*)out, 1024,
      2048LL * 1024, 2048, nullptr, nullptr, 0, 1.0f);
}

// Round 3
// 293.398 us; speedup vs baseline: 1.1053x; 1.0987x over previous
//
#include <hip/hip_runtime.h>
#include <hip/hip_bf16.h>
#include <stdint.h>

// ---------------------------------------------------------------------------
// SelfAttention: QKV = X@W + b ; S = QK^T/32 (mask -> -inf) ; O = softmax(S)@V
// B=4, S=2048, H=1024.  bf16 MFMA path.
// R3: mask compaction — ~50% of key columns are masked (Bernoulli mask), so
//     compact K/V to unmasked columns (device-side count, padded to 128).
//     Scores and PV GEMMs do ~half the FLOPs. Launch graph stays static:
//     worst-case grids + uniform early-exit reading cnt_pad[] from device.
// ---------------------------------------------------------------------------

typedef __attribute__((ext_vector_type(8))) short bf16x8;   // 8 bf16 = 4 VGPRs
typedef __attribute__((ext_vector_type(4))) float f32x4;

__device__ __forceinline__ void async_cp16(const void* g, void* l) {
  __builtin_amdgcn_global_load_lds(
      (const __attribute__((address_space(1))) void*)g,
      (__attribute__((address_space(3))) void*)l, 16, 0, 0);
}

// --------------------------- fp32 -> bf16 convert ---------------------------
__global__ void cvt_f32_bf16(const float* __restrict__ s,
                             __hip_bfloat16* __restrict__ d, int n) {
  int i = (blockIdx.x * blockDim.x + threadIdx.x) * 4;
  if (i >= n) return;
  float4 f = *(const float4*)(s + i);
  __hip_bfloat16 o[4];
  o[0] = __float2bfloat16(f.x);
  o[1] = __float2bfloat16(f.y);
  o[2] = __float2bfloat16(f.z);
  o[3] = __float2bfloat16(f.w);
  *(ushort4*)(d + i) = *(const ushort4*)o;
}

// -------------------- fp32 -> bf16 transposed (W -> W^T) --------------------
__global__ void transpose_cvt_f32(const float* __restrict__ src, int srcld,
                                  __hip_bfloat16* __restrict__ dst, int dstld) {
  __shared__ float tile[32][33];
  int bx = blockIdx.x * 32;   // src col
  int by = blockIdx.y * 32;   // src row
  int tx = threadIdx.x, ty = threadIdx.y;
#pragma unroll
  for (int j = 0; j < 4; ++j)
    tile[ty + j * 8][tx] = src[(int64_t)(by + ty + j * 8) * srcld + bx + tx];
  __syncthreads();
#pragma unroll
  for (int j = 0; j < 4; ++j)
    dst[(int64_t)(bx + ty + j * 8) * dstld + by + tx] =
        __float2bfloat16(tile[tx][ty + j * 8]);
}

// ------------------------------ mask scan ----------------------------------
// One block per batch. keep[j] = (mask[j]==0). Writes compacted index list,
// cnt[b], cnt_pad[b] (=round_up(cnt,128)).
__global__ __launch_bounds__(256) void mask_scan(const int* __restrict__ mask,
                                                 int* __restrict__ idx,
                                                 int* __restrict__ cnt,
                                                 int* __restrict__ cnt_pad) {
  const int b = blockIdx.x;
  mask += b * 2048;
  idx += b * 2048;
  const int t = threadIdx.x;
  const int lane = t & 63, wave = t >> 6;

  int keep[8];
  int local = 0;
#pragma unroll
  for (int j = 0; j < 8; ++j) {
    keep[j] = (mask[t * 8 + j] == 0);
    local += keep[j];
  }
  // inclusive wave scan
  int pre = local;
#pragma unroll
  for (int off = 1; off <= 32; off <<= 1) {
    int n = __shfl_up(pre, off, 64);
    if (lane >= off) pre += n;
  }
  __shared__ int wsum[4];
  if (lane == 63) wsum[wave] = pre;
  __syncthreads();
  int base = 0;
  for (int w = 0; w < wave; ++w) base += wsum[w];
  int excl = base + pre - local;
#pragma unroll
  for (int j = 0; j < 8; ++j)
    if (keep[j]) idx[excl++] = t * 8 + j;
  if (t == 255) {
    int tot = base + pre;
    cnt[b] = tot;
    cnt_pad[b] = (tot + 127) & ~127;
  }
}

// --------------------------- gather K rows ---------------------------------
// Kc[b][i][:] = QKV[b, idx[b][i], 1024:2048]; zero rows for i in [cnt,cnt_pad).
__global__ __launch_bounds__(256) void gather_k(
    const __hip_bfloat16* __restrict__ QKV, const int* __restrict__ idx,
    const int* __restrict__ cnt, const int* __restrict__ cnt_pad,
    __hip_bfloat16* __restrict__ Kc) {
  const int b = blockIdx.y;
  const int i = blockIdx.x;
  if (i >= cnt_pad[b]) return;
  const int t = threadIdx.x;  // 256 threads x ushort4 = 1024 bf16
  ushort4* dst = (ushort4*)(Kc + ((int64_t)b * 2048 + i) * 1024);
  if (i >= cnt[b]) {
    dst[t] = (ushort4){0, 0, 0, 0};
    return;
  }
  int sr = idx[b * 2048 + i];
  const ushort4* src =
      (const ushort4*)(QKV + ((int64_t)b * 2048 + sr) * 3072 + 1024);
  dst[t] = src[t];
}

// ---------------------- gather + transpose V ------------------------------
// Vt[b][d][i] = QKV[b, idx[b][i], 2048+d]; zero for i in [cnt,cnt_pad). ld=2048.
__global__ void gather_vt(const __hip_bfloat16* __restrict__ QKV,
                          const int* __restrict__ idx,
                          const int* __restrict__ cnt,
                          const int* __restrict__ cnt_pad,
                          __hip_bfloat16* __restrict__ Vt) {
  __shared__ __hip_bfloat16 tile[32][33];
  const int b = blockIdx.z;
  const int i0 = blockIdx.y * 32;
  if (i0 >= cnt_pad[b]) return;
  const int d0 = blockIdx.x * 32;
  const int tx = threadIdx.x, ty = threadIdx.y;
  const int cn = cnt[b];
#pragma unroll
  for (int j = 0; j < 4; ++j) {
    int i = i0 + ty + j * 8;
    unsigned short v = 0;
    if (i < cn)
      v = *(const unsigned short*)(QKV +
                                   ((int64_t)b * 2048 + idx[b * 2048 + i]) *
                                       3072 +
                                   2048 + d0 + tx);
    *(unsigned short*)&tile[ty + j * 8][tx] = v;
  }
  __syncthreads();
#pragma unroll
  for (int j = 0; j < 4; ++j)
    Vt[(int64_t)b * 1024 * 2048 + (int64_t)(d0 + ty + j * 8) * 2048 + i0 + tx] =
        tile[tx][ty + j * 8];
}

// ------------------------------- GEMM core ---------------------------------
// C[M][N] = A[M][K] @ Bt[N][K]^T.   128x128 tile, 256 thr (2x2 waves of 64x64),
// BK=32, mfma_f32_16x16x32_bf16. XOR-swizzled LDS (R2, conflict-free).
// MODE 0: C = acc + bias[n] -> bf16   (QKV projection)
// MODE 1: C = acc * scale   -> fp32   (scores / PV)
// NLIM: early-exit blocks with n0 >= Nlim[z].  KLIM: Ksize = Klim[z].
template <int MODE, bool NLIM, bool KLIM>
__global__ __launch_bounds__(256) void gemm_bt(
    const __hip_bfloat16* __restrict__ Abase, int lda, int64_t strideA,
    const __hip_bfloat16* __restrict__ Btbase, int ldb, int64_t strideB,
    void* __restrict__ Cbase, int ldc, int64_t strideC, int Ksize,
    const float* __restrict__ bias, const int* __restrict__ Nlim,
    const int* __restrict__ Klim, float scale) {
  const int z = blockIdx.z;
  const int n0 = blockIdx.x * 128;
  if (NLIM && n0 >= Nlim[z]) return;
  const int Ks = KLIM ? Klim[z] : Ksize;
  const __hip_bfloat16* A = Abase + z * strideA;
  const __hip_bfloat16* Bt = Btbase + z * strideB;

  const int tid = threadIdx.x;
  const int wave = tid >> 6, lane = tid & 63;
  const int quad = lane >> 4, tr = lane & 15;
  const int wm = wave & 1, wn = wave >> 1;
  const int m0 = blockIdx.y * 128;

  __shared__ __hip_bfloat16 lsA[128 * 32];
  __shared__ __hip_bfloat16 lsB[128 * 32];

  const __hip_bfloat16* gsrc[4];
  __hip_bfloat16* ldst[4];
  {
    const int srow = lane >> 2;
    const int kc = (((lane & 3) ^ ((lane >> 3) & 3)) * 8);
#pragma unroll
    for (int cc = 0; cc < 4; ++cc) {
      int c = wave * 4 + cc;
      int isA = (c < 8);
      int cr = isA ? c : (c - 8);
      int row = cr * 16 + srow;
      gsrc[cc] = isA ? (A + (int64_t)(m0 + row) * lda + kc)
                     : (Bt + (int64_t)(n0 + row) * ldb + kc);
      ldst[cc] = (isA ? lsA : lsB) + cr * 512;
    }
  }

  f32x4 acc[4][4];
#pragma unroll
  for (int mi = 0; mi < 4; ++mi)
#pragma unroll
    for (int ni = 0; ni < 4; ++ni) acc[mi][ni] = (f32x4){0.f, 0.f, 0.f, 0.f};

  const int slot = quad ^ ((tr >> 1) & 3);

  for (int k0 = 0; k0 < Ks; k0 += 32) {
    __syncthreads();
#pragma unroll
    for (int cc = 0; cc < 4; ++cc) async_cp16(gsrc[cc] + k0, ldst[cc]);
    __syncthreads();

    bf16x8 af[4], bfv[4];
#pragma unroll
    for (int mi = 0; mi < 4; ++mi)
      af[mi] = *(const bf16x8*)(lsA + (wm * 64 + mi * 16 + tr) * 32 + slot * 8);
#pragma unroll
    for (int ni = 0; ni < 4; ++ni)
      bfv[ni] = *(const bf16x8*)(lsB + (wn * 64 + ni * 16 + tr) * 32 + slot * 8);
#pragma unroll
    for (int mi = 0; mi < 4; ++mi)
#pragma unroll
      for (int ni = 0; ni < 4; ++ni)
        acc[mi][ni] = __builtin_amdgcn_mfma_f32_16x16x32_bf16(
            af[mi], bfv[ni], acc[mi][ni], 0, 0, 0);
  }

  // Epilogue. D element (row,col) in 16x16 tile = (quad*4 + r, tr)  [m89]
  const int rowbase = m0 + wm * 64;
  const int colbase = n0 + wn * 64;
  if (MODE == 0) {
    __hip_bfloat16* C = (__hip_bfloat16*)Cbase;
#pragma unroll
    for (int ni = 0; ni < 4; ++ni) {
      int col = colbase + ni * 16 + tr;
      float bv = bias[col];
#pragma unroll
      for (int mi = 0; mi < 4; ++mi) {
        int row = rowbase + mi * 16 + quad * 4;
#pragma unroll
        for (int r = 0; r < 4; ++r)
          C[(int64_t)(row + r) * ldc + col] =
              __float2bfloat16(acc[mi][ni][r] + bv);
      }
    }
  } else {
    float* C = (float*)Cbase + z * strideC;
#pragma unroll
    for (int ni = 0; ni < 4; ++ni) {
      int col = colbase + ni * 16 + tr;
#pragma unroll
      for (int mi = 0; mi < 4; ++mi) {
        int row = rowbase + mi * 16 + quad * 4;
#pragma unroll
        for (int r = 0; r < 4; ++r)
          C[(int64_t)(row + r) * ldc + col] = acc[mi][ni][r] * scale;
      }
    }
  }
}

// ------------------------------ row softmax --------------------------------
// One block per row of scores -> bf16 probabilities. Only cols < cnt[b] are
// valid; cols >= cnt get prob 0 (exact), so the PV GEMM's padded K range is
// multiply-by-zero.
__global__ __launch_bounds__(256) void softmax_rows(
    const float* __restrict__ Sc, __hip_bfloat16* __restrict__ P,
    const int* __restrict__ cnt) {
  const int64_t row = blockIdx.x;
  const int b = (int)(row >> 11);
  const int cn = cnt[b];
  const float4* s = (const float4*)(Sc + row * 2048);
  ushort4* p = (ushort4*)(P + row * 2048);
  const int t = threadIdx.x;
  const int wave = t >> 6, lane = t & 63;
  __shared__ float red[8];

  float4 v[2];
  v[0] = s[t];
  v[1] = s[t + 256];
  float* vf = (float*)v;
#pragma unroll
  for (int i = 0; i < 8; ++i) {
    int col = (i < 4) ? (t * 4 + i) : (1024 + t * 4 + (i - 4));
    if (col >= cn) vf[i] = -3.0e38f;
  }
  float mx = -3.0e38f;
#pragma unroll
  for (int i = 0; i < 8; ++i) mx = fmaxf(mx, vf[i]);
#pragma unroll
  for (int off = 32; off >= 1; off >>= 1) mx = fmaxf(mx, __shfl_xor(mx, off, 64));
  if (lane == 0) red[wave] = mx;
  __syncthreads();
  mx = fmaxf(fmaxf(red[0], red[1]), fmaxf(red[2], red[3]));

  float sum = 0.f;
#pragma unroll
  for (int i = 0; i < 8; ++i) {
    vf[i] = exp2f((vf[i] - mx) * 1.4426950408889634f);  // masked -> 0
    sum += vf[i];
  }
#pragma unroll
  for (int off = 32; off >= 1; off >>= 1) sum += __shfl_xor(sum, off, 64);
  if (lane == 0) red[4 + wave] = sum;
  __syncthreads();
  sum = red[4] + red[5] + red[6] + red[7];
  float inv = 1.0f / sum;

  ushort4 o[2];
#pragma unroll
  for (int j = 0; j < 2; ++j) {
    __hip_bfloat16 h[4];
#pragma unroll
    for (int r = 0; r < 4; ++r) h[r] = __float2bfloat16(vf[j * 4 + r] * inv);
    o[j] = *(const ushort4*)h;
  }
  p[t] = o[0];
  p[t + 256] = o[1];
}

// ------------------------------- launcher ----------------------------------
extern "C" void kernel_launch(void* const* d_in, const int* in_sizes, int n_in,
                              void* d_out, int out_size, void* d_ws,
                              size_t ws_size, hipStream_t stream) {
  const float* X = (const float*)d_in[0];        // (4,2048,1024) fp32
  const int* mask = (const int*)d_in[1];         // (4,2048) bool->int32
  const float* W = (const float*)d_in[2];        // (1024,3072) fp32
  const float* bias = (const float*)d_in[3];     // (3072,) fp32
  float* out = (float*)d_out;                    // (4,2048,1024) fp32

  char* ws = (char*)d_ws;
  auto alloc = [&](size_t bytes) {
    char* p = ws;
    ws += (bytes + 255) & ~(size_t)255;
    return p;
  };
  __hip_bfloat16* Xb = (__hip_bfloat16*)alloc(8192ULL * 1024 * 2);     // 16.8 MB
  __hip_bfloat16* Wt = (__hip_bfloat16*)alloc(3072ULL * 1024 * 2);     //  6.3 MB
  __hip_bfloat16* QKV = (__hip_bfloat16*)alloc(8192ULL * 3072 * 2);    // 50.3 MB
  __hip_bfloat16* Vt = (__hip_bfloat16*)alloc(4ULL * 1024 * 2048 * 2); // 16.8 MB
  float* Sc = (float*)alloc(4ULL * 2048 * 2048 * 4);                   // 67.1 MB
  __hip_bfloat16* P = (__hip_bfloat16*)alloc(4ULL * 2048 * 2048 * 2);  // 33.6 MB
  int* idx = (int*)alloc(4ULL * 2048 * 4);                             // 32 KB
  int* cnt = (int*)alloc(64);
  int* cnt_pad = (int*)alloc(64);
  // Kc reuses Xb's space (Xb is dead after the QKV GEMM).
  __hip_bfloat16* Kc = Xb;

  // 1) X -> bf16
  cvt_f32_bf16<<<8192, 256, 0, stream>>>(X, Xb, 8192 * 1024);
  // 2) W -> W^T bf16  (Bt layout [N][K])
  transpose_cvt_f32<<<dim3(96, 32, 1), dim3(32, 8), 0, stream>>>(W, 3072, Wt,
                                                                 1024);
  // 3) mask -> compacted index list
  mask_scan<<<4, 256, 0, stream>>>(mask, idx, cnt, cnt_pad);
  // 4) QKV = Xb @ Wt^T + bias  -> bf16 (8192 x 3072)
  gemm_bt<0, false, false><<<dim3(24, 64, 1), 256, 0, stream>>>(
      Xb, 1024, 0, Wt, 1024, 0, (void*)QKV, 3072, 0, 1024, bias, nullptr,
      nullptr, 1.0f);
  // 5) compact K rows (into Xb's space)
  gather_k<<<dim3(2048, 4), 256, 0, stream>>>(QKV, idx, cnt, cnt_pad, Kc);
  // 6) compact + transpose V
  gather_vt<<<dim3(32, 64, 4), dim3(32, 8), 0, stream>>>(QKV, idx, cnt, cnt_pad,
                                                         Vt);
  // 7) scores = Q @ Kc^T / 32  (fp32, per batch 2048 x cnt_pad)
  gemm_bt<1, true, false><<<dim3(16, 16, 4), 256, 0, stream>>>(
      QKV, 3072, 2048LL * 3072, Kc, 1024, 2048LL * 1024, (void*)Sc, 2048,
      2048LL * 2048, 1024, nullptr, cnt_pad, nullptr, 0.03125f);
  // 8) P = softmax(scores) over valid cols -> bf16 (pad cols = exact 0)
  softmax_rows<<<8192, 256, 0, stream>>>(Sc, P, cnt);
  // 9) out = P @ Vt^T  (fp32, per batch 2048x1024, K = cnt_pad)
  gemm_bt<1, false, true><<<dim3(8, 16, 4), 256, 0, stream>>>(
      P, 2048, 2048LL * 2048, Vt, 2048, 1024LL * 2048, (void*)out, 1024,
      2048LL * 1024, 0, nullptr, nullptr, cnt_pad, 1.0f);
}

// Round 4
// 279.984 us; speedup vs baseline: 1.1582x; 1.0479x over previous
//
#include <hip/hip_runtime.h>
#include <hip/hip_bf16.h>
#include <stdint.h>

// ---------------------------------------------------------------------------
// SelfAttention: QKV = X@W + b ; S = QK^T/32 (mask -> -inf) ; O = softmax(S)@V
// B=4, S=2048, H=1024.  bf16 MFMA path.
// R4: (a) split QKV: Q for all rows, K/V only for unmasked (compacted) rows —
//     GEMM1 FLOPs x2/3 and gather_k eliminated; (b) scores stored bf16 +
//     in-place bounds-limited softmax (~4x less softmax traffic).
//     Mask compaction state (idx/cnt/cnt_pad) lives on device; launch graph
//     is static with uniform early-exits.
// ---------------------------------------------------------------------------

typedef __attribute__((ext_vector_type(8))) short bf16x8;   // 8 bf16 = 4 VGPRs
typedef __attribute__((ext_vector_type(4))) float f32x4;

__device__ __forceinline__ void async_cp16(const void* g, void* l) {
  __builtin_amdgcn_global_load_lds(
      (const __attribute__((address_space(1))) void*)g,
      (__attribute__((address_space(3))) void*)l, 16, 0, 0);
}

// --------------------------- fp32 -> bf16 convert ---------------------------
__global__ void cvt_f32_bf16(const float* __restrict__ s,
                             __hip_bfloat16* __restrict__ d, int n) {
  int i = (blockIdx.x * blockDim.x + threadIdx.x) * 4;
  if (i >= n) return;
  float4 f = *(const float4*)(s + i);
  __hip_bfloat16 o[4];
  o[0] = __float2bfloat16(f.x);
  o[1] = __float2bfloat16(f.y);
  o[2] = __float2bfloat16(f.z);
  o[3] = __float2bfloat16(f.w);
  *(ushort4*)(d + i) = *(const ushort4*)o;
}

// -------------------- fp32 -> bf16 transposed (W -> W^T) --------------------
__global__ void transpose_cvt_f32(const float* __restrict__ src, int srcld,
                                  __hip_bfloat16* __restrict__ dst, int dstld) {
  __shared__ float tile[32][33];
  int bx = blockIdx.x * 32;   // src col
  int by = blockIdx.y * 32;   // src row
  int tx = threadIdx.x, ty = threadIdx.y;
#pragma unroll
  for (int j = 0; j < 4; ++j)
    tile[ty + j * 8][tx] = src[(int64_t)(by + ty + j * 8) * srcld + bx + tx];
  __syncthreads();
#pragma unroll
  for (int j = 0; j < 4; ++j)
    dst[(int64_t)(bx + ty + j * 8) * dstld + by + tx] =
        __float2bfloat16(tile[tx][ty + j * 8]);
}

// ------------------------------ mask scan ----------------------------------
// One block per batch. keep[j] = (mask[j]==0). Writes compacted index list,
// cnt[b], cnt_pad[b] (=round_up(cnt,128)).
__global__ __launch_bounds__(256) void mask_scan(const int* __restrict__ mask,
                                                 int* __restrict__ idx,
                                                 int* __restrict__ cnt,
                                                 int* __restrict__ cnt_pad) {
  const int b = blockIdx.x;
  mask += b * 2048;
  idx += b * 2048;
  const int t = threadIdx.x;
  const int lane = t & 63, wave = t >> 6;

  int keep[8];
  int local = 0;
#pragma unroll
  for (int j = 0; j < 8; ++j) {
    keep[j] = (mask[t * 8 + j] == 0);
    local += keep[j];
  }
  int pre = local;  // inclusive wave scan
#pragma unroll
  for (int off = 1; off <= 32; off <<= 1) {
    int n = __shfl_up(pre, off, 64);
    if (lane >= off) pre += n;
  }
  __shared__ int wsum[4];
  if (lane == 63) wsum[wave] = pre;
  __syncthreads();
  int base = 0;
  for (int w = 0; w < wave; ++w) base += wsum[w];
  int excl = base + pre - local;
#pragma unroll
  for (int j = 0; j < 8; ++j)
    if (keep[j]) idx[excl++] = t * 8 + j;
  if (t == 255) {
    int tot = base + pre;
    cnt[b] = tot;
    cnt_pad[b] = (tot + 127) & ~127;
  }
}

// --------------------------- gather X rows ---------------------------------
// Xc[b][i][:] = Xb[b, idx[b][i], :]; zero rows for i in [cnt, cnt_pad).
// (Zero pads keep pad K/V rows finite: 0*W + bias.)
__global__ __launch_bounds__(256) void gather_x(
    const __hip_bfloat16* __restrict__ Xb, const int* __restrict__ idx,
    const int* __restrict__ cnt, const int* __restrict__ cnt_pad,
    __hip_bfloat16* __restrict__ Xc) {
  const int b = blockIdx.y;
  const int i = blockIdx.x;
  if (i >= cnt_pad[b]) return;
  const int t = threadIdx.x;  // 256 threads x ushort4 = 1024 bf16
  ushort4* dst = (ushort4*)(Xc + ((int64_t)b * 2048 + i) * 1024);
  if (i >= cnt[b]) {
    dst[t] = (ushort4){0, 0, 0, 0};
    return;
  }
  int sr = idx[b * 2048 + i];
  const ushort4* src = (const ushort4*)(Xb + ((int64_t)b * 2048 + sr) * 1024);
  dst[t] = src[t];
}

// ------------------------- bf16 transpose (V -> V^T) ------------------------
// dst[d][i] = src[i][d], rows i limited to lim[z] (multiple of 128).
__global__ void transpose_bf16(const __hip_bfloat16* __restrict__ src, int srcld,
                               int64_t sstride,
                               __hip_bfloat16* __restrict__ dst, int dstld,
                               int64_t dstride, const int* __restrict__ lim) {
  __shared__ __hip_bfloat16 tile[32][33];
  const int z = blockIdx.z;
  const int i0 = blockIdx.y * 32;  // src row (key)
  if (i0 >= lim[z]) return;
  src += (int64_t)z * sstride;
  dst += (int64_t)z * dstride;
  const int d0 = blockIdx.x * 32;  // src col (d)
  const int tx = threadIdx.x, ty = threadIdx.y;
#pragma unroll
  for (int j = 0; j < 4; ++j)
    tile[ty + j * 8][tx] = src[(int64_t)(i0 + ty + j * 8) * srcld + d0 + tx];
  __syncthreads();
#pragma unroll
  for (int j = 0; j < 4; ++j)
    dst[(int64_t)(d0 + ty + j * 8) * dstld + i0 + tx] = tile[tx][ty + j * 8];
}

// ------------------------------- GEMM core ---------------------------------
// C[M][N] = A[M][K] @ Bt[N][K]^T.   128x128 tile, 256 thr (2x2 waves of 64x64),
// BK=32, mfma_f32_16x16x32_bf16. XOR-swizzled LDS (conflict-free, R2).
// MODE 0: C = acc + bias[n] -> bf16   (Q / KV projection)
// MODE 1: C = acc * scale   -> bf16   (scores)
// MODE 2: C = acc           -> fp32   (PV -> out)
// MLIM/NLIM: early-exit blocks with m0/n0 >= lim[z].  KLIM: Ksize = Klim[z].
template <int MODE, bool MLIM, bool NLIM, bool KLIM>
__global__ __launch_bounds__(256) void gemm_bt(
    const __hip_bfloat16* __restrict__ Abase, int lda, int64_t strideA,
    const __hip_bfloat16* __restrict__ Btbase, int ldb, int64_t strideB,
    void* __restrict__ Cbase, int ldc, int64_t strideC, int Ksize,
    const float* __restrict__ bias, const int* __restrict__ Mlim,
    const int* __restrict__ Nlim, const int* __restrict__ Klim, float scale) {
  const int z = blockIdx.z;
  const int m0 = blockIdx.y * 128, n0 = blockIdx.x * 128;
  if (MLIM && m0 >= Mlim[z]) return;
  if (NLIM && n0 >= Nlim[z]) return;
  const int Ks = KLIM ? Klim[z] : Ksize;
  const __hip_bfloat16* A = Abase + z * strideA;
  const __hip_bfloat16* Bt = Btbase + z * strideB;

  const int tid = threadIdx.x;
  const int wave = tid >> 6, lane = tid & 63;
  const int quad = lane >> 4, tr = lane & 15;
  const int wm = wave & 1, wn = wave >> 1;

  __shared__ __hip_bfloat16 lsA[128 * 32];
  __shared__ __hip_bfloat16 lsB[128 * 32];

  const __hip_bfloat16* gsrc[4];
  __hip_bfloat16* ldst[4];
  {
    const int srow = lane >> 2;
    const int kc = (((lane & 3) ^ ((lane >> 3) & 3)) * 8);
#pragma unroll
    for (int cc = 0; cc < 4; ++cc) {
      int c = wave * 4 + cc;
      int isA = (c < 8);
      int cr = isA ? c : (c - 8);
      int row = cr * 16 + srow;
      gsrc[cc] = isA ? (A + (int64_t)(m0 + row) * lda + kc)
                     : (Bt + (int64_t)(n0 + row) * ldb + kc);
      ldst[cc] = (isA ? lsA : lsB) + cr * 512;
    }
  }

  f32x4 acc[4][4];
#pragma unroll
  for (int mi = 0; mi < 4; ++mi)
#pragma unroll
    for (int ni = 0; ni < 4; ++ni) acc[mi][ni] = (f32x4){0.f, 0.f, 0.f, 0.f};

  const int slot = quad ^ ((tr >> 1) & 3);

  for (int k0 = 0; k0 < Ks; k0 += 32) {
    __syncthreads();
#pragma unroll
    for (int cc = 0; cc < 4; ++cc) async_cp16(gsrc[cc] + k0, ldst[cc]);
    __syncthreads();

    bf16x8 af[4], bfv[4];
#pragma unroll
    for (int mi = 0; mi < 4; ++mi)
      af[mi] = *(const bf16x8*)(lsA + (wm * 64 + mi * 16 + tr) * 32 + slot * 8);
#pragma unroll
    for (int ni = 0; ni < 4; ++ni)
      bfv[ni] = *(const bf16x8*)(lsB + (wn * 64 + ni * 16 + tr) * 32 + slot * 8);
#pragma unroll
    for (int mi = 0; mi < 4; ++mi)
#pragma unroll
      for (int ni = 0; ni < 4; ++ni)
        acc[mi][ni] = __builtin_amdgcn_mfma_f32_16x16x32_bf16(
            af[mi], bfv[ni], acc[mi][ni], 0, 0, 0);
  }

  // Epilogue. D element (row,col) in 16x16 tile = (quad*4 + r, tr)  [m89]
  const int rowbase = m0 + wm * 64;
  const int colbase = n0 + wn * 64;
  if (MODE == 0) {
    __hip_bfloat16* C = (__hip_bfloat16*)Cbase + z * strideC;
#pragma unroll
    for (int ni = 0; ni < 4; ++ni) {
      int col = colbase + ni * 16 + tr;
      float bv = bias[col];
#pragma unroll
      for (int mi = 0; mi < 4; ++mi) {
        int row = rowbase + mi * 16 + quad * 4;
#pragma unroll
        for (int r = 0; r < 4; ++r)
          C[(int64_t)(row + r) * ldc + col] =
              __float2bfloat16(acc[mi][ni][r] + bv);
      }
    }
  } else if (MODE == 1) {
    __hip_bfloat16* C = (__hip_bfloat16*)Cbase + z * strideC;
#pragma unroll
    for (int ni = 0; ni < 4; ++ni) {
      int col = colbase + ni * 16 + tr;
#pragma unroll
      for (int mi = 0; mi < 4; ++mi) {
        int row = rowbase + mi * 16 + quad * 4;
#pragma unroll
        for (int r = 0; r < 4; ++r)
          C[(int64_t)(row + r) * ldc + col] =
              __float2bfloat16(acc[mi][ni][r] * scale);
      }
    }
  } else {
    float* C = (float*)Cbase + z * strideC;
#pragma unroll
    for (int ni = 0; ni < 4; ++ni) {
      int col = colbase + ni * 16 + tr;
#pragma unroll
      for (int mi = 0; mi < 4; ++mi) {
        int row = rowbase + mi * 16 + quad * 4;
#pragma unroll
        for (int r = 0; r < 4; ++r)
          C[(int64_t)(row + r) * ldc + col] = acc[mi][ni][r];
      }
    }
  }
}

// ------------------------------ row softmax --------------------------------
// In-place bf16 softmax over one score row. Cols >= cnt[b] -> prob exactly 0;
// cols >= cnt_pad[b] untouched (never read downstream). Thread t owns the
// 16B chunk at cols [t*8, t*8+8).
__global__ __launch_bounds__(256) void softmax_rows(
    __hip_bfloat16* __restrict__ Sc, const int* __restrict__ cnt,
    const int* __restrict__ cnt_pad) {
  const int64_t row = blockIdx.x;
  const int b = (int)(row >> 11);
  const int cn = cnt[b];
  const int cp = cnt_pad[b];
  __hip_bfloat16* s = Sc + row * 2048;
  const int t = threadIdx.x;
  const int ct = t * 8;
  const bool act = (ct < cp);
  const int wave = t >> 6, lane = t & 63;
  __shared__ float red[8];

  float vf[8];
  if (act) {
    bf16x8 raw = *(const bf16x8*)(s + ct);
#pragma unroll
    for (int i = 0; i < 8; ++i) {
      unsigned int w = ((unsigned int)(unsigned short)raw[i]) << 16;
      vf[i] = (ct + i < cn) ? __uint_as_float(w) : -3.0e38f;
    }
  } else {
#pragma unroll
    for (int i = 0; i < 8; ++i) vf[i] = -3.0e38f;
  }

  float mx = -3.0e38f;
#pragma unroll
  for (int i = 0; i < 8; ++i) mx = fmaxf(mx, vf[i]);
#pragma unroll
  for (int off = 32; off >= 1; off >>= 1) mx = fmaxf(mx, __shfl_xor(mx, off, 64));
  if (lane == 0) red[wave] = mx;
  __syncthreads();
  mx = fmaxf(fmaxf(red[0], red[1]), fmaxf(red[2], red[3]));

  float sum = 0.f;
#pragma unroll
  for (int i = 0; i < 8; ++i) {
    vf[i] = exp2f((vf[i] - mx) * 1.4426950408889634f);  // masked -> 0
    sum += vf[i];
  }
#pragma unroll
  for (int off = 32; off >= 1; off >>= 1) sum += __shfl_xor(sum, off, 64);
  if (lane == 0) red[4 + wave] = sum;
  __syncthreads();
  sum = red[4] + red[5] + red[6] + red[7];
  float inv = 1.0f / sum;

  if (act) {
    __hip_bfloat16 h[8];
#pragma unroll
    for (int i = 0; i < 8; ++i) h[i] = __float2bfloat16(vf[i] * inv);
    *(bf16x8*)(s + ct) = *(const bf16x8*)h;
  }
}

// ------------------------------- launcher ----------------------------------
extern "C" void kernel_launch(void* const* d_in, const int* in_sizes, int n_in,
                              void* d_out, int out_size, void* d_ws,
                              size_t ws_size, hipStream_t stream) {
  const float* X = (const float*)d_in[0];        // (4,2048,1024) fp32
  const int* mask = (const int*)d_in[1];         // (4,2048) bool->int32
  const float* W = (const float*)d_in[2];        // (1024,3072) fp32
  const float* bias = (const float*)d_in[3];     // (3072,) fp32
  float* out = (float*)d_out;                    // (4,2048,1024) fp32

  char* ws = (char*)d_ws;
  auto alloc = [&](size_t bytes) {
    char* p = ws;
    ws += (bytes + 255) & ~(size_t)255;
    return p;
  };
  __hip_bfloat16* Xb = (__hip_bfloat16*)alloc(8192ULL * 1024 * 2);      // 16.8 MB
  __hip_bfloat16* Wt = (__hip_bfloat16*)alloc(3072ULL * 1024 * 2);      //  6.3 MB
  __hip_bfloat16* Q = (__hip_bfloat16*)alloc(8192ULL * 1024 * 2);       // 16.8 MB
  __hip_bfloat16* Xc = (__hip_bfloat16*)alloc(4ULL * 2048 * 1024 * 2);  // 16.8 MB
  __hip_bfloat16* KVc = (__hip_bfloat16*)alloc(4ULL * 2048 * 2048 * 2); // 33.6 MB
  __hip_bfloat16* Vt = (__hip_bfloat16*)alloc(4ULL * 1024 * 2048 * 2);  // 16.8 MB
  __hip_bfloat16* Sc = (__hip_bfloat16*)alloc(4ULL * 2048 * 2048 * 2);  // 33.6 MB
  int* idx = (int*)alloc(4ULL * 2048 * 4);
  int* cnt = (int*)alloc(64);
  int* cnt_pad = (int*)alloc(64);

  // 1) X -> bf16
  cvt_f32_bf16<<<8192, 256, 0, stream>>>(X, Xb, 8192 * 1024);
  // 2) W -> W^T bf16  (Bt layout [N][K])
  transpose_cvt_f32<<<dim3(96, 32, 1), dim3(32, 8), 0, stream>>>(W, 3072, Wt,
                                                                 1024);
  // 3) mask -> compacted index list
  mask_scan<<<4, 256, 0, stream>>>(mask, idx, cnt, cnt_pad);
  // 4) compact X rows (unmasked keys only)
  gather_x<<<dim3(2048, 4), 256, 0, stream>>>(Xb, idx, cnt, cnt_pad, Xc);
  // 5) Q = Xb @ Wt[0:1024]^T + b[0:1024]   (8192 x 1024 bf16)
  gemm_bt<0, false, false, false><<<dim3(8, 64, 1), 256, 0, stream>>>(
      Xb, 1024, 0, Wt, 1024, 0, (void*)Q, 1024, 0, 1024, bias, nullptr,
      nullptr, nullptr, 1.0f);
  // 6) KV = Xc @ Wt[1024:3072]^T + b[1024:3072]  (per batch cnt_pad x 2048)
  gemm_bt<0, true, false, false><<<dim3(16, 16, 4), 256, 0, stream>>>(
      Xc, 1024, 2048LL * 1024, Wt + 1024LL * 1024, 1024, 0, (void*)KVc, 2048,
      2048LL * 2048, 1024, bias + 1024, cnt_pad, nullptr, nullptr, 1.0f);
  // 7) Vt[b][d][i] = V[b][i][d]  (V = KVc cols 1024:2048), keys < cnt_pad
  transpose_bf16<<<dim3(32, 64, 4), dim3(32, 8), 0, stream>>>(
      KVc + 1024, 2048, 2048LL * 2048, Vt, 2048, 1024LL * 2048, cnt_pad);
  // 8) scores = Q @ Kc^T / 32 -> bf16 (per batch 2048 x cnt_pad)
  gemm_bt<1, false, true, false><<<dim3(16, 16, 4), 256, 0, stream>>>(
      Q, 1024, 2048LL * 1024, KVc, 2048, 2048LL * 2048, (void*)Sc, 2048,
      2048LL * 2048, 1024, nullptr, nullptr, cnt_pad, nullptr, 0.03125f);
  // 9) P = softmax(scores) in-place (pad cols in [cnt,cnt_pad) -> exact 0)
  softmax_rows<<<8192, 256, 0, stream>>>(Sc, cnt, cnt_pad);
  // 10) out = P @ Vt^T  (fp32, per batch 2048 x 1024, K = cnt_pad)
  gemm_bt<2, false, false, true><<<dim3(8, 16, 4), 256, 0, stream>>>(
      Sc, 2048, 2048LL * 2048, Vt, 2048, 1024LL * 2048, (void*)out, 1024,
      2048LL * 1024, 0, nullptr, nullptr, nullptr, cnt_pad, 1.0f);
}

// Round 5
// 267.297 us; speedup vs baseline: 1.2132x; 1.0475x over previous
//
#include <hip/hip_runtime.h>
#include <hip/hip_bf16.h>
#include <stdint.h>

// ---------------------------------------------------------------------------
// SelfAttention: QKV = X@W + b ; S = QK^T/32 (mask -> -inf) ; O = softmax(S)@V
// B=4, S=2048, H=1024.  bf16 MFMA path.
// R5: R4 was latency-bound (Occupancy 11%, 2 blocks/CU per GEMM dispatch).
//  (a) Q+KV merged into ONE dispatch (1536 blocks) with idx-indirect A-row
//      gather for the KV half — gather_x/Xc eliminated.
//  (b) scores/PV use a BN=64 GEMM variant -> 1024 active blocks each (4/CU).
// ---------------------------------------------------------------------------

typedef __attribute__((ext_vector_type(8))) short bf16x8;   // 8 bf16 = 4 VGPRs
typedef __attribute__((ext_vector_type(4))) float f32x4;

__device__ __forceinline__ void async_cp16(const void* g, void* l) {
  __builtin_amdgcn_global_load_lds(
      (const __attribute__((address_space(1))) void*)g,
      (__attribute__((address_space(3))) void*)l, 16, 0, 0);
}

// --------------------------- fp32 -> bf16 convert ---------------------------
__global__ void cvt_f32_bf16(const float* __restrict__ s,
                             __hip_bfloat16* __restrict__ d, int n) {
  int i = (blockIdx.x * blockDim.x + threadIdx.x) * 4;
  if (i >= n) return;
  float4 f = *(const float4*)(s + i);
  __hip_bfloat16 o[4];
  o[0] = __float2bfloat16(f.x);
  o[1] = __float2bfloat16(f.y);
  o[2] = __float2bfloat16(f.z);
  o[3] = __float2bfloat16(f.w);
  *(ushort4*)(d + i) = *(const ushort4*)o;
}

// -------------------- fp32 -> bf16 transposed (W -> W^T) --------------------
__global__ void transpose_cvt_f32(const float* __restrict__ src, int srcld,
                                  __hip_bfloat16* __restrict__ dst, int dstld) {
  __shared__ float tile[32][33];
  int bx = blockIdx.x * 32;   // src col
  int by = blockIdx.y * 32;   // src row
  int tx = threadIdx.x, ty = threadIdx.y;
#pragma unroll
  for (int j = 0; j < 4; ++j)
    tile[ty + j * 8][tx] = src[(int64_t)(by + ty + j * 8) * srcld + bx + tx];
  __syncthreads();
#pragma unroll
  for (int j = 0; j < 4; ++j)
    dst[(int64_t)(bx + ty + j * 8) * dstld + by + tx] =
        __float2bfloat16(tile[tx][ty + j * 8]);
}

// ------------------------------ mask scan ----------------------------------
// One block per batch. keep[j] = (mask[j]==0). Writes compacted index list,
// cnt[b], cnt_pad[b] (=round_up(cnt,128)).
__global__ __launch_bounds__(256) void mask_scan(const int* __restrict__ mask,
                                                 int* __restrict__ idx,
                                                 int* __restrict__ cnt,
                                                 int* __restrict__ cnt_pad) {
  const int b = blockIdx.x;
  mask += b * 2048;
  idx += b * 2048;
  const int t = threadIdx.x;
  const int lane = t & 63, wave = t >> 6;

  int keep[8];
  int local = 0;
#pragma unroll
  for (int j = 0; j < 8; ++j) {
    keep[j] = (mask[t * 8 + j] == 0);
    local += keep[j];
  }
  int pre = local;  // inclusive wave scan
#pragma unroll
  for (int off = 1; off <= 32; off <<= 1) {
    int n = __shfl_up(pre, off, 64);
    if (lane >= off) pre += n;
  }
  __shared__ int wsum[4];
  if (lane == 63) wsum[wave] = pre;
  __syncthreads();
  int base = 0;
  for (int w = 0; w < wave; ++w) base += wsum[w];
  int excl = base + pre - local;
#pragma unroll
  for (int j = 0; j < 8; ++j)
    if (keep[j]) idx[excl++] = t * 8 + j;
  if (t == 255) {
    int tot = base + pre;
    cnt[b] = tot;
    cnt_pad[b] = (tot + 127) & ~127;
  }
}

// ------------------------- bf16 transpose (V -> V^T) ------------------------
// dst[d][i] = src[i][d], rows i limited to lim[z] (multiple of 128).
__global__ void transpose_bf16(const __hip_bfloat16* __restrict__ src, int srcld,
                               int64_t sstride,
                               __hip_bfloat16* __restrict__ dst, int dstld,
                               int64_t dstride, const int* __restrict__ lim) {
  __shared__ __hip_bfloat16 tile[32][33];
  const int z = blockIdx.z;
  const int i0 = blockIdx.y * 32;  // src row (key)
  if (i0 >= lim[z]) return;
  src += (int64_t)z * sstride;
  dst += (int64_t)z * dstride;
  const int d0 = blockIdx.x * 32;  // src col (d)
  const int tx = threadIdx.x, ty = threadIdx.y;
#pragma unroll
  for (int j = 0; j < 4; ++j)
    tile[ty + j * 8][tx] = src[(int64_t)(i0 + ty + j * 8) * srcld + d0 + tx];
  __syncthreads();
#pragma unroll
  for (int j = 0; j < 4; ++j)
    dst[(int64_t)(d0 + ty + j * 8) * dstld + i0 + tx] = tile[tx][ty + j * 8];
}

// --------------------------- merged Q+KV GEMM ------------------------------
// grid (24, 16, B). bx<8: Q = Xb[z] @ Wt[0:1024]^T + b   (all 2048 rows)
//                  bx>=8: KV = gather(Xb[z], idx) @ Wt[1024:3072]^T + b
//                         (rows limited to cnt_pad[z]; pad rows clamp to
//                          idx 0 -> finite garbage, softmax zeroes them)
// 128x128 tile, 256 thr, BK=32, XOR-swizzled LDS (conflict-free).
__global__ __launch_bounds__(256) void gemm_qkv(
    const __hip_bfloat16* __restrict__ Xb, const __hip_bfloat16* __restrict__ Wt,
    const float* __restrict__ bias, const int* __restrict__ idx,
    const int* __restrict__ cnt, const int* __restrict__ cnt_pad,
    __hip_bfloat16* __restrict__ Q, __hip_bfloat16* __restrict__ KVc) {
  const int z = blockIdx.z;
  const int bx = blockIdx.x;
  const int m0 = blockIdx.y * 128;
  const bool isQ = (bx < 8);
  if (!isQ && m0 >= cnt_pad[z]) return;
  const int n0 = (isQ ? bx : bx - 8) * 128;
  const __hip_bfloat16* A = Xb + (int64_t)z * 2048 * 1024;
  const __hip_bfloat16* Bt = Wt + (isQ ? 0 : (int64_t)1024 * 1024);
  const float* bv = bias + (isQ ? 0 : 1024);

  const int tid = threadIdx.x;
  const int wave = tid >> 6, lane = tid & 63;
  const int quad = lane >> 4, tr = lane & 15;
  const int wm = wave & 1, wn = wave >> 1;

  __shared__ __hip_bfloat16 lsA[128 * 32];
  __shared__ __hip_bfloat16 lsB[128 * 32];

  const __hip_bfloat16* gsrc[4];
  __hip_bfloat16* ldst[4];
  {
    const int srow = lane >> 2;
    const int kc = (((lane & 3) ^ ((lane >> 3) & 3)) * 8);
    const int cz = isQ ? 0 : cnt[z];
    const int* idxz = idx + z * 2048;
#pragma unroll
    for (int cc = 0; cc < 4; ++cc) {
      int c = wave * 4 + cc;
      int isA = (c < 8);
      int cr = isA ? c : (c - 8);
      int row = cr * 16 + srow;
      if (isA) {
        int ar = m0 + row;
        if (!isQ) ar = (ar < cz) ? idxz[ar] : 0;
        gsrc[cc] = A + (int64_t)ar * 1024 + kc;
      } else {
        gsrc[cc] = Bt + (int64_t)(n0 + row) * 1024 + kc;
      }
      ldst[cc] = (isA ? lsA : lsB) + cr * 512;
    }
  }

  f32x4 acc[4][4];
#pragma unroll
  for (int mi = 0; mi < 4; ++mi)
#pragma unroll
    for (int ni = 0; ni < 4; ++ni) acc[mi][ni] = (f32x4){0.f, 0.f, 0.f, 0.f};

  const int slot = quad ^ ((tr >> 1) & 3);

  for (int k0 = 0; k0 < 1024; k0 += 32) {
    __syncthreads();
#pragma unroll
    for (int cc = 0; cc < 4; ++cc) async_cp16(gsrc[cc] + k0, ldst[cc]);
    __syncthreads();

    bf16x8 af[4], bfv[4];
#pragma unroll
    for (int mi = 0; mi < 4; ++mi)
      af[mi] = *(const bf16x8*)(lsA + (wm * 64 + mi * 16 + tr) * 32 + slot * 8);
#pragma unroll
    for (int ni = 0; ni < 4; ++ni)
      bfv[ni] = *(const bf16x8*)(lsB + (wn * 64 + ni * 16 + tr) * 32 + slot * 8);
#pragma unroll
    for (int mi = 0; mi < 4; ++mi)
#pragma unroll
      for (int ni = 0; ni < 4; ++ni)
        acc[mi][ni] = __builtin_amdgcn_mfma_f32_16x16x32_bf16(
            af[mi], bfv[ni], acc[mi][ni], 0, 0, 0);
  }

  // Epilogue. D element (row,col) in 16x16 tile = (quad*4 + r, tr)  [m89]
  const int rowbase = m0 + wm * 64;
  const int colbase = n0 + wn * 64;
  __hip_bfloat16* C;
  int ldc;
  if (isQ) {
    C = Q + (int64_t)z * 2048 * 1024;
    ldc = 1024;
  } else {
    C = KVc + (int64_t)z * 2048 * 2048;
    ldc = 2048;
  }
#pragma unroll
  for (int ni = 0; ni < 4; ++ni) {
    int col = colbase + ni * 16 + tr;
    float bb = bv[col];
#pragma unroll
    for (int mi = 0; mi < 4; ++mi) {
      int row = rowbase + mi * 16 + quad * 4;
#pragma unroll
      for (int r = 0; r < 4; ++r)
        C[(int64_t)(row + r) * ldc + col] = __float2bfloat16(acc[mi][ni][r] + bb);
    }
  }
}

// --------------------------- GEMM, 128x64 tile -----------------------------
// C[M][N] = A[M][K] @ Bt[N][K]^T.  256 thr = 4 waves, wave-tile 64x32
// (wm=wave&1 -> m, wn=wave>>1 -> n). BK=32. XOR-swizzled LDS.
// MODE 1: C = bf16(acc * scale)   (scores)
// MODE 2: C = acc  -> fp32        (PV -> out)
// NLIM: early-exit blocks with n0 >= Nlim[z].  KLIM: Ksize = Klim[z].
template <int MODE, bool NLIM, bool KLIM>
__global__ __launch_bounds__(256) void gemm_bt64(
    const __hip_bfloat16* __restrict__ Abase, int lda, int64_t strideA,
    const __hip_bfloat16* __restrict__ Btbase, int ldb, int64_t strideB,
    void* __restrict__ Cbase, int ldc, int64_t strideC, int Ksize,
    const int* __restrict__ Nlim, const int* __restrict__ Klim, float scale) {
  const int z = blockIdx.z;
  const int n0 = blockIdx.x * 64;
  if (NLIM && n0 >= Nlim[z]) return;
  const int Ks = KLIM ? Klim[z] : Ksize;
  const int m0 = blockIdx.y * 128;
  const __hip_bfloat16* A = Abase + z * strideA;
  const __hip_bfloat16* Bt = Btbase + z * strideB;

  const int tid = threadIdx.x;
  const int wave = tid >> 6, lane = tid & 63;
  const int quad = lane >> 4, tr = lane & 15;
  const int wm = wave & 1, wn = wave >> 1;

  __shared__ __hip_bfloat16 lsA[128 * 32];
  __shared__ __hip_bfloat16 lsB[64 * 32];

  // 12 chunks of 1KB: 0..7 = A rows, 8..11 = B rows. Wave w stages 3.
  const __hip_bfloat16* gsrc[3];
  __hip_bfloat16* ldst[3];
  {
    const int srow = lane >> 2;
    const int kc = (((lane & 3) ^ ((lane >> 3) & 3)) * 8);
#pragma unroll
    for (int cc = 0; cc < 3; ++cc) {
      int c = wave * 3 + cc;
      int isA = (c < 8);
      int cr = isA ? c : (c - 8);
      int row = cr * 16 + srow;
      gsrc[cc] = isA ? (A + (int64_t)(m0 + row) * lda + kc)
                     : (Bt + (int64_t)(n0 + row) * ldb + kc);
      ldst[cc] = (isA ? lsA : lsB) + cr * 512;
    }
  }

  f32x4 acc[4][2];
#pragma unroll
  for (int mi = 0; mi < 4; ++mi)
#pragma unroll
    for (int ni = 0; ni < 2; ++ni) acc[mi][ni] = (f32x4){0.f, 0.f, 0.f, 0.f};

  const int slot = quad ^ ((tr >> 1) & 3);

  for (int k0 = 0; k0 < Ks; k0 += 32) {
    __syncthreads();
#pragma unroll
    for (int cc = 0; cc < 3; ++cc) async_cp16(gsrc[cc] + k0, ldst[cc]);
    __syncthreads();

    bf16x8 af[4], bfv[2];
#pragma unroll
    for (int mi = 0; mi < 4; ++mi)
      af[mi] = *(const bf16x8*)(lsA + (wm * 64 + mi * 16 + tr) * 32 + slot * 8);
#pragma unroll
    for (int ni = 0; ni < 2; ++ni)
      bfv[ni] = *(const bf16x8*)(lsB + (wn * 32 + ni * 16 + tr) * 32 + slot * 8);
#pragma unroll
    for (int mi = 0; mi < 4; ++mi)
#pragma unroll
      for (int ni = 0; ni < 2; ++ni)
        acc[mi][ni] = __builtin_amdgcn_mfma_f32_16x16x32_bf16(
            af[mi], bfv[ni], acc[mi][ni], 0, 0, 0);
  }

  const int rowbase = m0 + wm * 64;
  const int colbase = n0 + wn * 32;
  if (MODE == 1) {
    __hip_bfloat16* C = (__hip_bfloat16*)Cbase + z * strideC;
#pragma unroll
    for (int ni = 0; ni < 2; ++ni) {
      int col = colbase + ni * 16 + tr;
#pragma unroll
      for (int mi = 0; mi < 4; ++mi) {
        int row = rowbase + mi * 16 + quad * 4;
#pragma unroll
        for (int r = 0; r < 4; ++r)
          C[(int64_t)(row + r) * ldc + col] =
              __float2bfloat16(acc[mi][ni][r] * scale);
      }
    }
  } else {
    float* C = (float*)Cbase + z * strideC;
#pragma unroll
    for (int ni = 0; ni < 2; ++ni) {
      int col = colbase + ni * 16 + tr;
#pragma unroll
      for (int mi = 0; mi < 4; ++mi) {
        int row = rowbase + mi * 16 + quad * 4;
#pragma unroll
        for (int r = 0; r < 4; ++r)
          C[(int64_t)(row + r) * ldc + col] = acc[mi][ni][r];
      }
    }
  }
}

// ------------------------------ row softmax --------------------------------
// In-place bf16 softmax over one score row. Cols >= cnt[b] -> prob exactly 0;
// cols >= cnt_pad[b] untouched (never read downstream).
__global__ __launch_bounds__(256) void softmax_rows(
    __hip_bfloat16* __restrict__ Sc, const int* __restrict__ cnt,
    const int* __restrict__ cnt_pad) {
  const int64_t row = blockIdx.x;
  const int b = (int)(row >> 11);
  const int cn = cnt[b];
  const int cp = cnt_pad[b];
  __hip_bfloat16* s = Sc + row * 2048;
  const int t = threadIdx.x;
  const int ct = t * 8;
  const bool act = (ct < cp);
  const int wave = t >> 6, lane = t & 63;
  __shared__ float red[8];

  float vf[8];
  if (act) {
    bf16x8 raw = *(const bf16x8*)(s + ct);
#pragma unroll
    for (int i = 0; i < 8; ++i) {
      unsigned int w = ((unsigned int)(unsigned short)raw[i]) << 16;
      vf[i] = (ct + i < cn) ? __uint_as_float(w) : -3.0e38f;
    }
  } else {
#pragma unroll
    for (int i = 0; i < 8; ++i) vf[i] = -3.0e38f;
  }

  float mx = -3.0e38f;
#pragma unroll
  for (int i = 0; i < 8; ++i) mx = fmaxf(mx, vf[i]);
#pragma unroll
  for (int off = 32; off >= 1; off >>= 1) mx = fmaxf(mx, __shfl_xor(mx, off, 64));
  if (lane == 0) red[wave] = mx;
  __syncthreads();
  mx = fmaxf(fmaxf(red[0], red[1]), fmaxf(red[2], red[3]));

  float sum = 0.f;
#pragma unroll
  for (int i = 0; i < 8; ++i) {
    vf[i] = exp2f((vf[i] - mx) * 1.4426950408889634f);  // masked -> 0
    sum += vf[i];
  }
#pragma unroll
  for (int off = 32; off >= 1; off >>= 1) sum += __shfl_xor(sum, off, 64);
  if (lane == 0) red[4 + wave] = sum;
  __syncthreads();
  sum = red[4] + red[5] + red[6] + red[7];
  float inv = 1.0f / sum;

  if (act) {
    __hip_bfloat16 h[8];
#pragma unroll
    for (int i = 0; i < 8; ++i) h[i] = __float2bfloat16(vf[i] * inv);
    *(bf16x8*)(s + ct) = *(const bf16x8*)h;
  }
}

// ------------------------------- launcher ----------------------------------
extern "C" void kernel_launch(void* const* d_in, const int* in_sizes, int n_in,
                              void* d_out, int out_size, void* d_ws,
                              size_t ws_size, hipStream_t stream) {
  const float* X = (const float*)d_in[0];        // (4,2048,1024) fp32
  const int* mask = (const int*)d_in[1];         // (4,2048) bool->int32
  const float* W = (const float*)d_in[2];        // (1024,3072) fp32
  const float* bias = (const float*)d_in[3];     // (3072,) fp32
  float* out = (float*)d_out;                    // (4,2048,1024) fp32

  char* ws = (char*)d_ws;
  auto alloc = [&](size_t bytes) {
    char* p = ws;
    ws += (bytes + 255) & ~(size_t)255;
    return p;
  };
  __hip_bfloat16* Xb = (__hip_bfloat16*)alloc(8192ULL * 1024 * 2);      // 16.8 MB
  __hip_bfloat16* Wt = (__hip_bfloat16*)alloc(3072ULL * 1024 * 2);      //  6.3 MB
  __hip_bfloat16* Q = (__hip_bfloat16*)alloc(8192ULL * 1024 * 2);       // 16.8 MB
  __hip_bfloat16* KVc = (__hip_bfloat16*)alloc(4ULL * 2048 * 2048 * 2); // 33.6 MB
  __hip_bfloat16* Vt = (__hip_bfloat16*)alloc(4ULL * 1024 * 2048 * 2);  // 16.8 MB
  __hip_bfloat16* Sc = (__hip_bfloat16*)alloc(4ULL * 2048 * 2048 * 2);  // 33.6 MB
  int* idx = (int*)alloc(4ULL * 2048 * 4);
  int* cnt = (int*)alloc(64);
  int* cnt_pad = (int*)alloc(64);

  // 1) X -> bf16
  cvt_f32_bf16<<<8192, 256, 0, stream>>>(X, Xb, 8192 * 1024);
  // 2) W -> W^T bf16  (Bt layout [N][K])
  transpose_cvt_f32<<<dim3(96, 32, 1), dim3(32, 8), 0, stream>>>(W, 3072, Wt,
                                                                 1024);
  // 3) mask -> compacted index list
  mask_scan<<<4, 256, 0, stream>>>(mask, idx, cnt, cnt_pad);
  // 4) merged: Q (all rows) + KV (compacted rows, gathered in staging)
  gemm_qkv<<<dim3(24, 16, 4), 256, 0, stream>>>(Xb, Wt, bias, idx, cnt,
                                                cnt_pad, Q, KVc);
  // 5) Vt[b][d][i] = V[b][i][d]  (V = KVc cols 1024:2048), keys < cnt_pad
  transpose_bf16<<<dim3(32, 64, 4), dim3(32, 8), 0, stream>>>(
      KVc + 1024, 2048, 2048LL * 2048, Vt, 2048, 1024LL * 2048, cnt_pad);
  // 6) scores = Q @ Kc^T / 32 -> bf16 (per batch 2048 x cnt_pad), BN=64
  gemm_bt64<1, true, false><<<dim3(32, 16, 4), 256, 0, stream>>>(
      Q, 1024, 2048LL * 1024, KVc, 2048, 2048LL * 2048, (void*)Sc, 2048,
      2048LL * 2048, 1024, cnt_pad, nullptr, 0.03125f);
  // 7) P = softmax(scores) in-place (pad cols in [cnt,cnt_pad) -> exact 0)
  softmax_rows<<<8192, 256, 0, stream>>>(Sc, cnt, cnt_pad);
  // 8) out = P @ Vt^T  (fp32, per batch 2048 x 1024, K = cnt_pad), BN=64
  gemm_bt64<2, false, true><<<dim3(16, 16, 4), 256, 0, stream>>>(
      Sc, 2048, 2048LL * 2048, Vt, 2048, 1024LL * 2048, (void*)out, 1024,
      2048LL * 1024, 0, nullptr, cnt_pad, 1.0f);
}

// Round 6
// 244.506 us; speedup vs baseline: 1.3263x; 1.0932x over previous
//
#include <hip/hip_runtime.h>
#include <hip/hip_bf16.h>
#include <stdint.h>

// ---------------------------------------------------------------------------
// SelfAttention: QKV = X@W + b ; S = QK^T/32 (mask -> -inf) ; O = softmax(S)@V
// B=4, S=2048, H=1024.  bf16 MFMA path.
// R6: all GEMMs were latency-bound on k-loop global loads (R5: ~1200 cyc/iter
//     vs ~110 compute; FETCH 3x ideal from XCD-scattered tile reuse).
//  (a) XCD-aware block swizzle: xcd = flat&7 picks a 2x4 (m,n) tile cluster
//      (m interleaved mod 2, n mod 4) -> per-XCD working set ~3 MB fits the
//      4 MB XCD L2 -> k-loop loads hit L2 (~200cyc) not HBM (~900cyc).
//  (b) gemm_qkv writes V^T directly (packed ushort4) -> transpose dispatch
//      eliminated.
// ---------------------------------------------------------------------------

typedef __attribute__((ext_vector_type(8))) short bf16x8;   // 8 bf16 = 4 VGPRs
typedef __attribute__((ext_vector_type(4))) float f32x4;

__device__ __forceinline__ void async_cp16(const void* g, void* l) {
  __builtin_amdgcn_global_load_lds(
      (const __attribute__((address_space(1))) void*)g,
      (__attribute__((address_space(3))) void*)l, 16, 0, 0);
}

// --------------------------- fp32 -> bf16 convert ---------------------------
__global__ void cvt_f32_bf16(const float* __restrict__ s,
                             __hip_bfloat16* __restrict__ d, int n) {
  int i = (blockIdx.x * blockDim.x + threadIdx.x) * 4;
  if (i >= n) return;
  float4 f = *(const float4*)(s + i);
  __hip_bfloat16 o[4];
  o[0] = __float2bfloat16(f.x);
  o[1] = __float2bfloat16(f.y);
  o[2] = __float2bfloat16(f.z);
  o[3] = __float2bfloat16(f.w);
  *(ushort4*)(d + i) = *(const ushort4*)o;
}

// -------------------- fp32 -> bf16 transposed (W -> W^T) --------------------
__global__ void transpose_cvt_f32(const float* __restrict__ src, int srcld,
                                  __hip_bfloat16* __restrict__ dst, int dstld) {
  __shared__ float tile[32][33];
  int bx = blockIdx.x * 32;   // src col
  int by = blockIdx.y * 32;   // src row
  int tx = threadIdx.x, ty = threadIdx.y;
#pragma unroll
  for (int j = 0; j < 4; ++j)
    tile[ty + j * 8][tx] = src[(int64_t)(by + ty + j * 8) * srcld + bx + tx];
  __syncthreads();
#pragma unroll
  for (int j = 0; j < 4; ++j)
    dst[(int64_t)(bx + ty + j * 8) * dstld + by + tx] =
        __float2bfloat16(tile[tx][ty + j * 8]);
}

// ------------------------------ mask scan ----------------------------------
__global__ __launch_bounds__(256) void mask_scan(const int* __restrict__ mask,
                                                 int* __restrict__ idx,
                                                 int* __restrict__ cnt,
                                                 int* __restrict__ cnt_pad) {
  const int b = blockIdx.x;
  mask += b * 2048;
  idx += b * 2048;
  const int t = threadIdx.x;
  const int lane = t & 63, wave = t >> 6;

  int keep[8];
  int local = 0;
#pragma unroll
  for (int j = 0; j < 8; ++j) {
    keep[j] = (mask[t * 8 + j] == 0);
    local += keep[j];
  }
  int pre = local;  // inclusive wave scan
#pragma unroll
  for (int off = 1; off <= 32; off <<= 1) {
    int n = __shfl_up(pre, off, 64);
    if (lane >= off) pre += n;
  }
  __shared__ int wsum[4];
  if (lane == 63) wsum[wave] = pre;
  __syncthreads();
  int base = 0;
  for (int w = 0; w < wave; ++w) base += wsum[w];
  int excl = base + pre - local;
#pragma unroll
  for (int j = 0; j < 8; ++j)
    if (keep[j]) idx[excl++] = t * 8 + j;
  if (t == 255) {
    int tot = base + pre;
    cnt[b] = tot;
    cnt_pad[b] = (tot + 127) & ~127;
  }
}

// --------------------------- merged Q+K+V GEMM -----------------------------
// grid (384, 1, B).  Swizzled flat id: xcd=f&7, loc=f>>3 in [0,48):
//   m_idx = (loc&7)*2 + (xcd>>2)   in [0,16)   (m0 = m_idx*128)
//   n_idx = (loc>>3)*4 + (xcd&3)   in [0,24)
// n_idx<8:  Q  = Xb[z] @ Wt[0:1024]^T + b      (all 2048 rows)
// n_idx>=8: KV = gather(Xb[z], idx) @ Wt[1024:3072]^T + b, rows < cnt_pad[z]
//   KV cols [0,1024)  -> Kc[key][col]         (ld 1024)
//   KV cols [1024,2048)-> Vt[col-1024][key]   (transposed, packed ushort4)
// 128x128 tile, 256 thr, BK=32, XOR-swizzled LDS (conflict-free).
__global__ __launch_bounds__(256) void gemm_qkv(
    const __hip_bfloat16* __restrict__ Xb, const __hip_bfloat16* __restrict__ Wt,
    const float* __restrict__ bias, const int* __restrict__ idx,
    const int* __restrict__ cnt, const int* __restrict__ cnt_pad,
    __hip_bfloat16* __restrict__ Q, __hip_bfloat16* __restrict__ Kc,
    __hip_bfloat16* __restrict__ Vt) {
  const int z = blockIdx.z;
  const int f = blockIdx.x;
  const int xcd = f & 7, loc = f >> 3;
  const int m0 = ((loc & 7) * 2 + (xcd >> 2)) * 128;
  const int n_idx = (loc >> 3) * 4 + (xcd & 3);
  const bool isQ = (n_idx < 8);
  if (!isQ && m0 >= cnt_pad[z]) return;
  const int n0 = (isQ ? n_idx : n_idx - 8) * 128;
  const __hip_bfloat16* A = Xb + (int64_t)z * 2048 * 1024;
  const __hip_bfloat16* Bt = Wt + (isQ ? 0 : (int64_t)1024 * 1024);
  const float* bv = bias + (isQ ? 0 : 1024);

  const int tid = threadIdx.x;
  const int wave = tid >> 6, lane = tid & 63;
  const int quad = lane >> 4, tr = lane & 15;
  const int wm = wave & 1, wn = wave >> 1;

  __shared__ __hip_bfloat16 lsA[128 * 32];
  __shared__ __hip_bfloat16 lsB[128 * 32];

  const __hip_bfloat16* gsrc[4];
  __hip_bfloat16* ldst[4];
  {
    const int srow = lane >> 2;
    const int kc = (((lane & 3) ^ ((lane >> 3) & 3)) * 8);
    const int cz = isQ ? 0 : cnt[z];
    const int* idxz = idx + z * 2048;
#pragma unroll
    for (int cc = 0; cc < 4; ++cc) {
      int c = wave * 4 + cc;
      int isA = (c < 8);
      int cr = isA ? c : (c - 8);
      int row = cr * 16 + srow;
      if (isA) {
        int ar = m0 + row;
        if (!isQ) ar = (ar < cz) ? idxz[ar] : 0;
        gsrc[cc] = A + (int64_t)ar * 1024 + kc;
      } else {
        gsrc[cc] = Bt + (int64_t)(n0 + row) * 1024 + kc;
      }
      ldst[cc] = (isA ? lsA : lsB) + cr * 512;
    }
  }

  f32x4 acc[4][4];
#pragma unroll
  for (int mi = 0; mi < 4; ++mi)
#pragma unroll
    for (int ni = 0; ni < 4; ++ni) acc[mi][ni] = (f32x4){0.f, 0.f, 0.f, 0.f};

  const int slot = quad ^ ((tr >> 1) & 3);

  for (int k0 = 0; k0 < 1024; k0 += 32) {
    __syncthreads();
#pragma unroll
    for (int cc = 0; cc < 4; ++cc) async_cp16(gsrc[cc] + k0, ldst[cc]);
    __syncthreads();

    bf16x8 af[4], bfv[4];
#pragma unroll
    for (int mi = 0; mi < 4; ++mi)
      af[mi] = *(const bf16x8*)(lsA + (wm * 64 + mi * 16 + tr) * 32 + slot * 8);
#pragma unroll
    for (int ni = 0; ni < 4; ++ni)
      bfv[ni] = *(const bf16x8*)(lsB + (wn * 64 + ni * 16 + tr) * 32 + slot * 8);
#pragma unroll
    for (int mi = 0; mi < 4; ++mi)
#pragma unroll
      for (int ni = 0; ni < 4; ++ni)
        acc[mi][ni] = __builtin_amdgcn_mfma_f32_16x16x32_bf16(
            af[mi], bfv[ni], acc[mi][ni], 0, 0, 0);
  }

  // Epilogue. D element (row,col) in 16x16 tile = (quad*4 + r, tr)  [m89]
  const int rowbase = m0 + wm * 64;
  const int colbase = n0 + wn * 64;
  if (isQ) {
    __hip_bfloat16* C = Q + (int64_t)z * 2048 * 1024;
#pragma unroll
    for (int ni = 0; ni < 4; ++ni) {
      int col = colbase + ni * 16 + tr;
      float bb = bv[col];
#pragma unroll
      for (int mi = 0; mi < 4; ++mi) {
        int row = rowbase + mi * 16 + quad * 4;
#pragma unroll
        for (int r = 0; r < 4; ++r)
          C[(int64_t)(row + r) * 1024 + col] =
              __float2bfloat16(acc[mi][ni][r] + bb);
      }
    }
  } else if (n0 < 1024) {  // K half
    __hip_bfloat16* C = Kc + (int64_t)z * 2048 * 1024;
#pragma unroll
    for (int ni = 0; ni < 4; ++ni) {
      int col = colbase + ni * 16 + tr;
      float bb = bv[col];
#pragma unroll
      for (int mi = 0; mi < 4; ++mi) {
        int row = rowbase + mi * 16 + quad * 4;
#pragma unroll
        for (int r = 0; r < 4; ++r)
          C[(int64_t)(row + r) * 1024 + col] =
              __float2bfloat16(acc[mi][ni][r] + bb);
      }
    }
  } else {  // V half -> transposed, packed 4-key runs
    __hip_bfloat16* C = Vt + (int64_t)z * 1024 * 2048;
#pragma unroll
    for (int ni = 0; ni < 4; ++ni) {
      int col = colbase + ni * 16 + tr;  // 1024..2047
      float bb = bv[col];
      int d = col - 1024;
#pragma unroll
      for (int mi = 0; mi < 4; ++mi) {
        int row = rowbase + mi * 16 + quad * 4;
        __hip_bfloat16 h[4];
#pragma unroll
        for (int r = 0; r < 4; ++r) h[r] = __float2bfloat16(acc[mi][ni][r] + bb);
        *(ushort4*)(C + (int64_t)d * 2048 + row) = *(const ushort4*)h;
      }
    }
  }
}

// --------------------------- GEMM, 128x64 tile -----------------------------
// C[M][N] = A[M][K] @ Bt[N][K]^T.  256 thr = 4 waves, wave-tile 64x32.
// Swizzled flat grid (NT*16 blocks): xcd=f&7, loc=f>>3:
//   m_idx=(loc%8)*2+(xcd>>2) in [0,16); n_idx=(loc/8)*4+(xcd&3) in [0,NT).
// BK=32. XOR-swizzled LDS.
// MODE 1: C = bf16(acc * scale)   (scores)
// MODE 2: C = acc  -> fp32        (PV -> out)
// NLIM: early-exit blocks with n0 >= Nlim[z].  KLIM: Ksize = Klim[z].
template <int MODE, bool NLIM, bool KLIM, int NT>
__global__ __launch_bounds__(256) void gemm_bt64(
    const __hip_bfloat16* __restrict__ Abase, int lda, int64_t strideA,
    const __hip_bfloat16* __restrict__ Btbase, int ldb, int64_t strideB,
    void* __restrict__ Cbase, int ldc, int64_t strideC, int Ksize,
    const int* __restrict__ Nlim, const int* __restrict__ Klim, float scale) {
  const int z = blockIdx.z;
  const int f = blockIdx.x;
  const int xcd = f & 7, loc = f >> 3;
  const int m0 = ((loc & 7) * 2 + (xcd >> 2)) * 128;
  const int n0 = ((loc >> 3) * 4 + (xcd & 3)) * 64;
  if (NLIM && n0 >= Nlim[z]) return;
  const int Ks = KLIM ? Klim[z] : Ksize;
  const __hip_bfloat16* A = Abase + z * strideA;
  const __hip_bfloat16* Bt = Btbase + z * strideB;

  const int tid = threadIdx.x;
  const int wave = tid >> 6, lane = tid & 63;
  const int quad = lane >> 4, tr = lane & 15;
  const int wm = wave & 1, wn = wave >> 1;

  __shared__ __hip_bfloat16 lsA[128 * 32];
  __shared__ __hip_bfloat16 lsB[64 * 32];

  // 12 chunks of 1KB: 0..7 = A rows, 8..11 = B rows. Wave w stages 3.
  const __hip_bfloat16* gsrc[3];
  __hip_bfloat16* ldst[3];
  {
    const int srow = lane >> 2;
    const int kc = (((lane & 3) ^ ((lane >> 3) & 3)) * 8);
#pragma unroll
    for (int cc = 0; cc < 3; ++cc) {
      int c = wave * 3 + cc;
      int isA = (c < 8);
      int cr = isA ? c : (c - 8);
      int row = cr * 16 + srow;
      gsrc[cc] = isA ? (A + (int64_t)(m0 + row) * lda + kc)
                     : (Bt + (int64_t)(n0 + row) * ldb + kc);
      ldst[cc] = (isA ? lsA : lsB) + cr * 512;
    }
  }

  f32x4 acc[4][2];
#pragma unroll
  for (int mi = 0; mi < 4; ++mi)
#pragma unroll
    for (int ni = 0; ni < 2; ++ni) acc[mi][ni] = (f32x4){0.f, 0.f, 0.f, 0.f};

  const int slot = quad ^ ((tr >> 1) & 3);

  for (int k0 = 0; k0 < Ks; k0 += 32) {
    __syncthreads();
#pragma unroll
    for (int cc = 0; cc < 3; ++cc) async_cp16(gsrc[cc] + k0, ldst[cc]);
    __syncthreads();

    bf16x8 af[4], bfv[2];
#pragma unroll
    for (int mi = 0; mi < 4; ++mi)
      af[mi] = *(const bf16x8*)(lsA + (wm * 64 + mi * 16 + tr) * 32 + slot * 8);
#pragma unroll
    for (int ni = 0; ni < 2; ++ni)
      bfv[ni] = *(const bf16x8*)(lsB + (wn * 32 + ni * 16 + tr) * 32 + slot * 8);
#pragma unroll
    for (int mi = 0; mi < 4; ++mi)
#pragma unroll
      for (int ni = 0; ni < 2; ++ni)
        acc[mi][ni] = __builtin_amdgcn_mfma_f32_16x16x32_bf16(
            af[mi], bfv[ni], acc[mi][ni], 0, 0, 0);
  }

  const int rowbase = m0 + wm * 64;
  const int colbase = n0 + wn * 32;
  if (MODE == 1) {
    __hip_bfloat16* C = (__hip_bfloat16*)Cbase + z * strideC;
#pragma unroll
    for (int ni = 0; ni < 2; ++ni) {
      int col = colbase + ni * 16 + tr;
#pragma unroll
      for (int mi = 0; mi < 4; ++mi) {
        int row = rowbase + mi * 16 + quad * 4;
#pragma unroll
        for (int r = 0; r < 4; ++r)
          C[(int64_t)(row + r) * ldc + col] =
              __float2bfloat16(acc[mi][ni][r] * scale);
      }
    }
  } else {
    float* C = (float*)Cbase + z * strideC;
#pragma unroll
    for (int ni = 0; ni < 2; ++ni) {
      int col = colbase + ni * 16 + tr;
#pragma unroll
      for (int mi = 0; mi < 4; ++mi) {
        int row = rowbase + mi * 16 + quad * 4;
#pragma unroll
        for (int r = 0; r < 4; ++r)
          C[(int64_t)(row + r) * ldc + col] = acc[mi][ni][r];
      }
    }
  }
}

// ------------------------------ row softmax --------------------------------
// In-place bf16 softmax over one score row. Cols >= cnt[b] -> prob exactly 0;
// cols >= cnt_pad[b] untouched (never read downstream).
__global__ __launch_bounds__(256) void softmax_rows(
    __hip_bfloat16* __restrict__ Sc, const int* __restrict__ cnt,
    const int* __restrict__ cnt_pad) {
  const int64_t row = blockIdx.x;
  const int b = (int)(row >> 11);
  const int cn = cnt[b];
  const int cp = cnt_pad[b];
  __hip_bfloat16* s = Sc + row * 2048;
  const int t = threadIdx.x;
  const int ct = t * 8;
  const bool act = (ct < cp);
  const int wave = t >> 6, lane = t & 63;
  __shared__ float red[8];

  float vf[8];
  if (act) {
    bf16x8 raw = *(const bf16x8*)(s + ct);
#pragma unroll
    for (int i = 0; i < 8; ++i) {
      unsigned int w = ((unsigned int)(unsigned short)raw[i]) << 16;
      vf[i] = (ct + i < cn) ? __uint_as_float(w) : -3.0e38f;
    }
  } else {
#pragma unroll
    for (int i = 0; i < 8; ++i) vf[i] = -3.0e38f;
  }

  float mx = -3.0e38f;
#pragma unroll
  for (int i = 0; i < 8; ++i) mx = fmaxf(mx, vf[i]);
#pragma unroll
  for (int off = 32; off >= 1; off >>= 1) mx = fmaxf(mx, __shfl_xor(mx, off, 64));
  if (lane == 0) red[wave] = mx;
  __syncthreads();
  mx = fmaxf(fmaxf(red[0], red[1]), fmaxf(red[2], red[3]));

  float sum = 0.f;
#pragma unroll
  for (int i = 0; i < 8; ++i) {
    vf[i] = exp2f((vf[i] - mx) * 1.4426950408889634f);  // masked -> 0
    sum += vf[i];
  }
#pragma unroll
  for (int off = 32; off >= 1; off >>= 1) sum += __shfl_xor(sum, off, 64);
  if (lane == 0) red[4 + wave] = sum;
  __syncthreads();
  sum = red[4] + red[5] + red[6] + red[7];
  float inv = 1.0f / sum;

  if (act) {
    __hip_bfloat16 h[8];
#pragma unroll
    for (int i = 0; i < 8; ++i) h[i] = __float2bfloat16(vf[i] * inv);
    *(bf16x8*)(s + ct) = *(const bf16x8*)h;
  }
}

// ------------------------------- launcher ----------------------------------
extern "C" void kernel_launch(void* const* d_in, const int* in_sizes, int n_in,
                              void* d_out, int out_size, void* d_ws,
                              size_t ws_size, hipStream_t stream) {
  const float* X = (const float*)d_in[0];        // (4,2048,1024) fp32
  const int* mask = (const int*)d_in[1];         // (4,2048) bool->int32
  const float* W = (const float*)d_in[2];        // (1024,3072) fp32
  const float* bias = (const float*)d_in[3];     // (3072,) fp32
  float* out = (float*)d_out;                    // (4,2048,1024) fp32

  char* ws = (char*)d_ws;
  auto alloc = [&](size_t bytes) {
    char* p = ws;
    ws += (bytes + 255) & ~(size_t)255;
    return p;
  };
  __hip_bfloat16* Xb = (__hip_bfloat16*)alloc(8192ULL * 1024 * 2);      // 16.8 MB
  __hip_bfloat16* Wt = (__hip_bfloat16*)alloc(3072ULL * 1024 * 2);      //  6.3 MB
  __hip_bfloat16* Q = (__hip_bfloat16*)alloc(8192ULL * 1024 * 2);       // 16.8 MB
  __hip_bfloat16* Kc = (__hip_bfloat16*)alloc(4ULL * 2048 * 1024 * 2);  // 16.8 MB
  __hip_bfloat16* Vt = (__hip_bfloat16*)alloc(4ULL * 1024 * 2048 * 2);  // 16.8 MB
  __hip_bfloat16* Sc = (__hip_bfloat16*)alloc(4ULL * 2048 * 2048 * 2);  // 33.6 MB
  int* idx = (int*)alloc(4ULL * 2048 * 4);
  int* cnt = (int*)alloc(64);
  int* cnt_pad = (int*)alloc(64);

  // 1) X -> bf16
  cvt_f32_bf16<<<8192, 256, 0, stream>>>(X, Xb, 8192 * 1024);
  // 2) W -> W^T bf16  (Bt layout [N][K])
  transpose_cvt_f32<<<dim3(96, 32, 1), dim3(32, 8), 0, stream>>>(W, 3072, Wt,
                                                                 1024);
  // 3) mask -> compacted index list
  mask_scan<<<4, 256, 0, stream>>>(mask, idx, cnt, cnt_pad);
  // 4) merged Q + K + V^T (swizzled, V transposed in epilogue)
  gemm_qkv<<<dim3(384, 1, 4), 256, 0, stream>>>(Xb, Wt, bias, idx, cnt,
                                                cnt_pad, Q, Kc, Vt);
  // 5) scores = Q @ Kc^T / 32 -> bf16 (per batch 2048 x cnt_pad), BN=64
  gemm_bt64<1, true, false, 32><<<dim3(512, 1, 4), 256, 0, stream>>>(
      Q, 1024, 2048LL * 1024, Kc, 1024, 2048LL * 1024, (void*)Sc, 2048,
      2048LL * 2048, 1024, cnt_pad, nullptr, 0.03125f);
  // 6) P = softmax(scores) in-place (pad cols in [cnt,cnt_pad) -> exact 0)
  softmax_rows<<<8192, 256, 0, stream>>>(Sc, cnt, cnt_pad);
  // 7) out = P @ Vt^T  (fp32, per batch 2048 x 1024, K = cnt_pad), BN=64
  gemm_bt64<2, false, true, 16><<<dim3(256, 1, 4), 256, 0, stream>>>(
      Sc, 2048, 2048LL * 2048, Vt, 2048, 1024LL * 2048, (void*)out, 1024,
      2048LL * 1024, 0, nullptr, cnt_pad, 1.0f);
}